// Round 16
// baseline (406.909 us; speedup 1.0000x reference)
//
#include <hip/hip_runtime.h>
#include <hip/hip_bf16.h>
#include <math.h>

#define N_NODES 50000
#define NE      800000
#define D       128
#define H       8
#define DH      16
#define NLAYER  2
#define IN_F    128
#define PP      8192
#define FF      256
#define MPAD    50048   // 391 * 128 = 782 * 64
#define CAP     96      // bucket capacity (mean deg 16; P(>=96)~1e-40)
#define NBIN    196     // bins of 256 nodes: bin = d >> 8
#define BCAP    48      // per-chunk per-bin LDS cap
#define GCAP    4608    // per-bin global cap
#define CHUNK   2048    // edges per phase-1 block

typedef short  bf16x8 __attribute__((ext_vector_type(8)));
typedef float  f32x4  __attribute__((ext_vector_type(4)));
typedef __hip_bfloat16 bf16;
typedef unsigned short u16;
typedef unsigned int   u32;

__device__ __forceinline__ float bflo(u32 u) { return __uint_as_float(u << 16); }
__device__ __forceinline__ float bfhi(u32 u) { return __uint_as_float(u & 0xffff0000u); }
__device__ __forceinline__ u16 bfbits(float f) { bf16 t = __float2bfloat16(f); return *(u16*)&t; }

// Phase 1: bin edges by dst>>8 via LDS, flush dense appends to per-bin global arrays.
__global__ __launch_bounds__(256) void bin_kernel(
    const int* __restrict__ dst, const int* __restrict__ src,
    u32* __restrict__ gbin, int* __restrict__ gbin_cnt)
{
    __shared__ u32 ent[NBIN * BCAP];
    __shared__ int bcnt[NBIN];
    const int t = threadIdx.x, l = blockIdx.y;
    const int base = blockIdx.x * CHUNK;
    if (t < NBIN) bcnt[t] = 0;
    __syncthreads();
    #pragma unroll
    for (int j = 0; j < CHUNK / 256; j++) {
        int e = base + j * 256 + t;
        if (e < NE) {
            int d = dst[(size_t)l * NE + e];
            int s = src[(size_t)l * NE + e];
            int bin = d >> 8;
            int slot = atomicAdd(&bcnt[bin], 1);
            if (slot < BCAP) ent[bin * BCAP + slot] = ((u32)s << 16) | (u32)(d & 255);
        }
    }
    __syncthreads();
    if (t < NBIN) {
        int c = bcnt[t]; if (c > BCAP) c = BCAP;
        if (c > 0) {
            int gb = atomicAdd(&gbin_cnt[l * NBIN + t], c);
            u32* gp = gbin + ((size_t)l * NBIN + t) * GCAP;
            for (int i = 0; i < c; i++)
                if (gb + i < GCAP) gp[gb + i] = ent[t * BCAP + i];
        }
    }
}

// Phase 2: per (bin, layer) block expands packed edges into CAP-buckets via LDS counters.
__global__ __launch_bounds__(256) void expand_kernel(
    const u32* __restrict__ gbin, const int* __restrict__ gbin_cnt,
    int* __restrict__ cnt, u16* __restrict__ ssrc)
{
    __shared__ int lcnt[256];
    const int t = threadIdx.x, b = blockIdx.x, l = blockIdx.y;
    lcnt[t] = 0;
    __syncthreads();
    int n = gbin_cnt[l * NBIN + b]; if (n > GCAP) n = GCAP;
    const u32* gp = gbin + ((size_t)l * NBIN + b) * GCAP;
    for (int i = t; i < n; i += 256) {
        u32 u = gp[i];
        int dl = (int)(u & 255);
        int pos = atomicAdd(&lcnt[dl], 1);
        if (pos < CAP) {
            int d = (b << 8) + dl;
            ssrc[((size_t)l * N_NODES + d) * CAP + pos] = (u16)(u >> 16);
        }
    }
    __syncthreads();
    int d = (b << 8) + t;
    if (d < N_NODES) cnt[l * N_NODES + d] = lcnt[t];
}

// One-shot weight prep: transpose+bf16 all weights, KV-interleaved QKV perm, bias cat,
// and gbin_cnt zeroing (replaces the memset launch).
__global__ void prep_kernel(const float* __restrict__ W_in,
                            const float* __restrict__ Wq, const float* __restrict__ Wk,
                            const float* __restrict__ Wv, const float* __restrict__ Wo,
                            const float* __restrict__ Wf1, const float* __restrict__ Wf2,
                            const float* __restrict__ bq, const float* __restrict__ bk,
                            const float* __restrict__ bv,
                            bf16* __restrict__ win_t, bf16* __restrict__ wqkv_t,
                            bf16* __restrict__ wo_t, bf16* __restrict__ wf1_t,
                            bf16* __restrict__ wf2_t, float* __restrict__ bqkv,
                            int* __restrict__ gbin_cnt)
{
    int id = blockIdx.x * blockDim.x + threadIdx.x;
    if (id < 16384) {
        int n = id >> 7, k = id & 127;
        win_t[id] = __float2bfloat16(W_in[k * 128 + n]);
        return;
    }
    id -= 16384;
    if (id < NLAYER * 49152) {           // QKV, rows permuted for kv-interleave
        int l = id / 49152, j = id % 49152;
        int r = j >> 7, k = j & 127;
        const float* Ws; int col;
        if (r < 128) { Ws = Wq; col = r; }
        else {
            int u = r - 128, hh = u >> 5, w = u & 31;
            if (w < 16) { Ws = Wk; col = hh * 16 + w; }
            else        { Ws = Wv; col = hh * 16 + w - 16; }
        }
        wqkv_t[(size_t)l * 49152 + j] = __float2bfloat16(Ws[(size_t)l * 16384 + k * 128 + col]);
        return;
    }
    id -= NLAYER * 49152;
    if (id < NLAYER * 16384) {
        int l = id / 16384, j = id % 16384;
        int n = j >> 7, k = j & 127;
        wo_t[id] = __float2bfloat16(Wo[(size_t)l * 16384 + k * 128 + n]);
        return;
    }
    id -= NLAYER * 16384;
    if (id < NLAYER * 32768) {           // wf1: [256][128] from [128][256]
        int l = id / 32768, j = id % 32768;
        int n = j >> 7, k = j & 127;
        wf1_t[id] = __float2bfloat16(Wf1[(size_t)l * 32768 + k * 256 + n]);
        return;
    }
    id -= NLAYER * 32768;
    if (id < NLAYER * 32768) {           // wf2: [128][256] from [256][128]
        int l = id / 32768, j = id % 32768;
        int n = j >> 8, k = j & 255;
        wf2_t[id] = __float2bfloat16(Wf2[(size_t)l * 32768 + k * 128 + n]);
        return;
    }
    id -= NLAYER * 32768;
    if (id < NLAYER * 384) {             // bias cat with same perm
        int l = id / 384, r = id % 384;
        float v;
        if (r < 128) v = bq[l * 128 + r];
        else {
            int u = r - 128, hh = u >> 5, w = u & 31;
            v = (w < 16) ? bk[l * 128 + hh * 16 + w] : bv[l * 128 + hh * 16 + w - 16];
        }
        bqkv[l * 384 + r] = v;
        return;
    }
    id -= NLAYER * 384;
    if (id < 2 * NBIN) gbin_cnt[id] = 0;
}

// Fused head: h = x @ W_in + b_in (f32 write) ; qkv0 = bf16(h) @ Wqkv0 + bqkv0.
// 64-row tile; bf16(x) and bf16(h) staged in LDS; K-chunk order identical to the
// previous gemm_mfma path -> bit-identical results.
__global__ __launch_bounds__(256) void head_fused(
    const float* __restrict__ x, const bf16* __restrict__ win_t,
    const float* __restrict__ b_in,
    const bf16* __restrict__ wqkv0, const float* __restrict__ bqkv0,
    float* __restrict__ h, bf16* __restrict__ qkvb)
{
    __shared__ char lds[65536];
    char* Axb = lds;            // 64 x 256B bf16(x), swizzled
    char* Hb  = lds + 16384;    // 64 x 256B bf16(h0), swizzled
    char* Bs  = lds + 32768;    // 32KB weight buffer
    const int t = threadIdx.x;
    const int w = t >> 6, lane = t & 63;
    const int r0 = blockIdx.x * 64;
    const int c = lane & 15, sub = lane >> 4;

    // stage bf16(x): 64 rows x 128 f32 -> bf16 LDS (zero pad rows)
    {
        int row = t >> 2;
        int col0 = (t & 3) * 32;
        int grow = r0 + row;
        #pragma unroll
        for (int j = 0; j < 8; j++) {
            float4 v = make_float4(0.f, 0.f, 0.f, 0.f);
            if (grow < N_NODES) v = *(const float4*)(x + (size_t)grow * 128 + col0 + j * 4);
            u32 lo = ((u32)bfbits(v.y) << 16) | bfbits(v.x);
            u32 hi = ((u32)bfbits(v.w) << 16) | bfbits(v.z);
            int byte = (col0 + j * 4) * 2;
            int addr = row * 256 + ((byte & ~15) ^ ((row & 7) << 4)) + (byte & 15);
            *(u32*)(Axb + addr)     = lo;
            *(u32*)(Axb + addr + 4) = hi;
        }
    }
    // stage win_t fully: 128 rows x 256B
    {
        int row = t >> 1;
        int off = (t & 1) * 128;
        const char* bp = (const char*)win_t + row * 256 + off;
        #pragma unroll
        for (int j = 0; j < 8; j++) {
            float4 v = *(const float4*)(bp + j * 16);
            *(float4*)(Bs + row * 256 + ((off + j * 16) ^ ((row & 7) << 4))) = v;
        }
    }
    __syncthreads();

    // h0 = xb @ win + b_in (K=128); wave: 16 rows x 128 cols
    f32x4 acc0[8] = {};
    #pragma unroll
    for (int kc = 0; kc < 2; kc++) {
        #pragma unroll
        for (int kk = 0; kk < 2; kk++) {
            int kbyte = (kc * 2 + kk) * 64 + sub * 16;
            int rowa = w * 16 + c;
            bf16x8 af = *(const bf16x8*)(Axb + rowa * 256 + (kbyte ^ ((rowa & 7) << 4)));
            #pragma unroll
            for (int n = 0; n < 8; n++) {
                int rowb = n * 16 + c;
                bf16x8 bf8 = *(const bf16x8*)(Bs + rowb * 256 + (kbyte ^ ((rowb & 7) << 4)));
                acc0[n] = __builtin_amdgcn_mfma_f32_16x16x32_bf16(af, bf8, acc0[n], 0, 0, 0);
            }
        }
    }

    // epilogue A: h f32 (guarded) + Hb LDS (bf16, all rows)
    #pragma unroll
    for (int i = 0; i < 4; i++) {
        int lrow = w * 16 + sub * 4 + i;
        int grow = r0 + lrow;
        bool ok = grow < N_NODES;
        #pragma unroll
        for (int n = 0; n < 8; n++) {
            float v = acc0[n][i] + b_in[n * 16 + c];
            if (ok) h[(size_t)grow * D + n * 16 + c] = v;
            int byte = (n * 16 + c) * 2;
            int addr = lrow * 256 + ((byte & ~15) ^ ((lrow & 7) << 4)) + (byte & 15);
            *(u16*)(Hb + addr) = bfbits(v);
        }
    }
    __syncthreads();

    // qkv0 = h0b @ wqkv0 + bqkv0 (K=128, Nc=384 in 3 chunks of 128 cols)
    #pragma unroll
    for (int cc = 0; cc < 3; cc++) {
        {   // stage wqkv rows [cc*128, cc*128+128): 128 x 256B
            int row = t >> 1;
            int off = (t & 1) * 128;
            const char* bp = (const char*)wqkv0 + (size_t)(cc * 128 + row) * 256 + off;
            #pragma unroll
            for (int j = 0; j < 8; j++) {
                float4 v = *(const float4*)(bp + j * 16);
                *(float4*)(Bs + row * 256 + ((off + j * 16) ^ ((row & 7) << 4))) = v;
            }
        }
        __syncthreads();
        f32x4 acc[8] = {};
        #pragma unroll
        for (int kc = 0; kc < 2; kc++) {
            #pragma unroll
            for (int kk = 0; kk < 2; kk++) {
                int kbyte = (kc * 2 + kk) * 64 + sub * 16;
                int rowa = w * 16 + c;
                bf16x8 af = *(const bf16x8*)(Hb + rowa * 256 + (kbyte ^ ((rowa & 7) << 4)));
                #pragma unroll
                for (int n = 0; n < 8; n++) {
                    int rowb = n * 16 + c;
                    bf16x8 bf8 = *(const bf16x8*)(Bs + rowb * 256 + (kbyte ^ ((rowb & 7) << 4)));
                    acc[n] = __builtin_amdgcn_mfma_f32_16x16x32_bf16(af, bf8, acc[n], 0, 0, 0);
                }
            }
        }
        #pragma unroll
        for (int i = 0; i < 4; i++) {
            int grow = r0 + w * 16 + sub * 4 + i;
            #pragma unroll
            for (int n = 0; n < 8; n++) {
                int col = cc * 128 + n * 16 + c;
                qkvb[(size_t)grow * 384 + col] = __float2bfloat16(acc[n][i] + bqkv0[col]);
            }
        }
        __syncthreads();
    }
}

// Fused layer tail: h = LN2( LN1(h + agg@Wo + bo) + FFN(LN1(...)) ), optionally
// followed by next layer's QKV projection from the LN2 output (kept in LDS).
__global__ __launch_bounds__(256) void tail_fused(
    const bf16* __restrict__ qkv,    // agg in q-section, lda=384
    const bf16* __restrict__ wo_t,   // [128][128]
    const float* __restrict__ bo,
    const float* __restrict__ g1, const float* __restrict__ be1,
    const bf16* __restrict__ Wf1t,   // [256][128]
    const float* __restrict__ b1,
    const bf16* __restrict__ Wf2t,   // [128][256]
    const float* __restrict__ b2,
    const float* __restrict__ g2, const float* __restrict__ be2,
    float* __restrict__ h,
    const bf16* __restrict__ wqkv_next, const float* __restrict__ bqkv_next,
    bf16* __restrict__ qkvb_out)
{
    __shared__ char lds[81920];
    char* AsA = lds;                 // part1: 64 x 128B A-chunk (overlaps Ah1)
    char* Ah1 = lds;                 // part2: 64 x 256B h1 (bf16, swizzled)
    char* Xs  = lds + 16384;         // 64 x 512B hidden X; later reused as h2b (64 x 256B)
    char* Bs  = lds + 49152;         // 32KB weight chunk buffer
    const int t = threadIdx.x;
    const int w = t >> 6, lane = t & 63;
    const int r0 = blockIdx.x * 64;
    const int c = lane & 15, sub = lane >> 4;

    // ---- part 1: T = agg @ Wo (K=128) ----
    f32x4 acc0[8] = {};
    #pragma unroll
    for (int k0 = 0; k0 < 128; k0 += 64) {
        {
            int row = t >> 2;
            int c16 = (t & 3) * 32;
            const char* ap = (const char*)(qkv + (size_t)(r0 + row) * 384 + k0);
            float4 a0 = *(const float4*)(ap + c16);
            float4 a1 = *(const float4*)(ap + c16 + 16);
            *(float4*)(AsA + row * 128 + ((c16)      ^ ((row & 7) << 4))) = a0;
            *(float4*)(AsA + row * 128 + ((c16 + 16) ^ ((row & 7) << 4))) = a1;
        }
        {
            int row = t >> 1;
            int c16 = (t & 1) * 64;
            const char* bp = (const char*)(wo_t + (size_t)row * 128 + k0);
            #pragma unroll
            for (int j = 0; j < 4; j++) {
                float4 b = *(const float4*)(bp + c16 + j * 16);
                *(float4*)(Bs + row * 128 + ((c16 + j * 16) ^ ((row & 7) << 4))) = b;
            }
        }
        __syncthreads();
        #pragma unroll
        for (int kk = 0; kk < 2; kk++) {
            int kbyte = kk * 64 + sub * 16;
            int rowa = w * 16 + c;
            bf16x8 af = *(const bf16x8*)(AsA + rowa * 128 + (kbyte ^ ((rowa & 7) << 4)));
            #pragma unroll
            for (int n = 0; n < 8; n++) {
                int rowb = n * 16 + c;
                bf16x8 bf8 = *(const bf16x8*)(Bs + rowb * 128 + (kbyte ^ ((rowb & 7) << 4)));
                acc0[n] = __builtin_amdgcn_mfma_f32_16x16x32_bf16(af, bf8, acc0[n], 0, 0, 0);
            }
        }
        __syncthreads();
    }

    // ---- LN1: h1 in regs + Ah1 in LDS (bf16) ----
    float h1v[8][4];
    {
        float bsv[8], gv[8], bev[8];
        #pragma unroll
        for (int n = 0; n < 8; n++) {
            int col = n * 16 + c;
            bsv[n] = bo[col]; gv[n] = g1[col]; bev[n] = be1[col];
        }
        #pragma unroll
        for (int i = 0; i < 4; i++) {
            int row = r0 + w * 16 + sub * 4 + i;
            bool ok = row < N_NODES;
            float x[8];
            float s = 0.f;
            #pragma unroll
            for (int n = 0; n < 8; n++) {
                float res = ok ? h[(size_t)row * D + n * 16 + c] : 0.f;
                x[n] = res + acc0[n][i] + bsv[n];
                s += x[n];
            }
            s += __shfl_xor(s, 1); s += __shfl_xor(s, 2);
            s += __shfl_xor(s, 4); s += __shfl_xor(s, 8);
            float mean = s * (1.f / 128.f);
            float v = 0.f;
            #pragma unroll
            for (int n = 0; n < 8; n++) { float dd = x[n] - mean; v += dd * dd; }
            v += __shfl_xor(v, 1); v += __shfl_xor(v, 2);
            v += __shfl_xor(v, 4); v += __shfl_xor(v, 8);
            float rstd = rsqrtf(v * (1.f / 128.f) + 1e-5f);
            int lrow = w * 16 + sub * 4 + i;
            #pragma unroll
            for (int n = 0; n < 8; n++) {
                float o = (x[n] - mean) * rstd * gv[n] + bev[n];
                h1v[n][i] = o;
                int byte = (n * 16 + c) * 2;
                int addr = lrow * 256 + ((byte & ~15) ^ ((lrow & 7) << 4)) + (byte & 15);
                *(u16*)(Ah1 + addr) = bfbits(o);
            }
        }
    }
    __syncthreads();

    // ---- part 2: X = relu(h1 @ Wf1 + b1), K=128 in 2 chunks of 64 ----
    f32x4 acc1[16] = {};
    #pragma unroll
    for (int kc = 0; kc < 2; kc++) {
        {
            int row = t;
            const char* bp = (const char*)Wf1t + row * 256 + kc * 128;
            #pragma unroll
            for (int j = 0; j < 8; j++) {
                float4 v = *(const float4*)(bp + j * 16);
                *(float4*)(Bs + row * 128 + ((j * 16) ^ ((row & 7) << 4))) = v;
            }
        }
        __syncthreads();
        #pragma unroll
        for (int kkl = 0; kkl < 2; kkl++) {
            int abyte = (kc * 2 + kkl) * 64 + sub * 16;
            int rowa = w * 16 + c;
            bf16x8 af = *(const bf16x8*)(Ah1 + rowa * 256 + (abyte ^ ((rowa & 7) << 4)));
            int bbyte = kkl * 64 + sub * 16;
            #pragma unroll
            for (int n = 0; n < 16; n++) {
                int rowb = n * 16 + c;
                bf16x8 bf8 = *(const bf16x8*)(Bs + rowb * 128 + (bbyte ^ ((rowb & 7) << 4)));
                acc1[n] = __builtin_amdgcn_mfma_f32_16x16x32_bf16(af, bf8, acc1[n], 0, 0, 0);
            }
        }
        __syncthreads();
    }

    // bias + relu + X to LDS (bf16, 512B rows, swizzled)
    #pragma unroll
    for (int n = 0; n < 16; n++) {
        float bs = b1[n * 16 + c];
        #pragma unroll
        for (int i = 0; i < 4; i++) {
            int row = w * 16 + sub * 4 + i;
            float v = fmaxf(acc1[n][i] + bs, 0.f);
            int byte = (n * 16 + c) * 2;
            int addr = row * 512 + ((byte & ~15) ^ ((row & 7) << 4)) + (byte & 15);
            *(u16*)(Xs + addr) = bfbits(v);
        }
    }
    __syncthreads();

    // ---- part 3: Y = X @ Wf2 (K=256 in 2 chunks of 128) ----
    f32x4 acc2[8] = {};
    #pragma unroll
    for (int kc = 0; kc < 2; kc++) {
        {
            int row = t >> 1;
            int off = (t & 1) * 128;
            const char* bp = (const char*)Wf2t + row * 512 + kc * 256 + off;
            #pragma unroll
            for (int j = 0; j < 8; j++) {
                float4 v = *(const float4*)(bp + j * 16);
                *(float4*)(Bs + row * 256 + ((off + j * 16) ^ ((row & 7) << 4))) = v;
            }
        }
        __syncthreads();
        #pragma unroll
        for (int kkl = 0; kkl < 4; kkl++) {
            int xbyte = kc * 256 + kkl * 64 + sub * 16;
            int rowa = w * 16 + c;
            bf16x8 af = *(const bf16x8*)(Xs + rowa * 512 + (xbyte ^ ((rowa & 7) << 4)));
            int bbyte = kkl * 64 + sub * 16;
            #pragma unroll
            for (int n = 0; n < 8; n++) {
                int rowb = n * 16 + c;
                bf16x8 bf8 = *(const bf16x8*)(Bs + rowb * 256 + (bbyte ^ ((rowb & 7) << 4)));
                acc2[n] = __builtin_amdgcn_mfma_f32_16x16x32_bf16(af, bf8, acc2[n], 0, 0, 0);
            }
        }
        __syncthreads();
    }

    // ---- LN2 epilogue: h f32 (guarded) + h2b into Xs (bf16, all rows) ----
    {
        float bsv[8], gv[8], bev[8];
        #pragma unroll
        for (int n = 0; n < 8; n++) {
            int col = n * 16 + c;
            bsv[n] = b2[col]; gv[n] = g2[col]; bev[n] = be2[col];
        }
        #pragma unroll
        for (int i = 0; i < 4; i++) {
            int lrow = w * 16 + sub * 4 + i;
            int grow = r0 + lrow;
            bool ok = grow < N_NODES;
            float x[8];
            float s = 0.f;
            #pragma unroll
            for (int n = 0; n < 8; n++) {
                x[n] = h1v[n][i] + acc2[n][i] + bsv[n];
                s += x[n];
            }
            s += __shfl_xor(s, 1); s += __shfl_xor(s, 2);
            s += __shfl_xor(s, 4); s += __shfl_xor(s, 8);
            float mean = s * (1.f / 128.f);
            float v = 0.f;
            #pragma unroll
            for (int n = 0; n < 8; n++) { float dd = x[n] - mean; v += dd * dd; }
            v += __shfl_xor(v, 1); v += __shfl_xor(v, 2);
            v += __shfl_xor(v, 4); v += __shfl_xor(v, 8);
            float rstd = rsqrtf(v * (1.f / 128.f) + 1e-5f);
            #pragma unroll
            for (int n = 0; n < 8; n++) {
                float o = (x[n] - mean) * rstd * gv[n] + bev[n];
                if (ok) h[(size_t)grow * D + n * 16 + c] = o;
                int byte = (n * 16 + c) * 2;
                int addr = lrow * 256 + ((byte & ~15) ^ ((lrow & 7) << 4)) + (byte & 15);
                *(u16*)(Xs + addr) = bfbits(o);
            }
        }
    }

    // ---- part D (optional): next layer's QKV from h2b ----
    if (wqkv_next) {
        #pragma unroll
        for (int cc = 0; cc < 3; cc++) {
            {
                int row = t >> 1;
                int off = (t & 1) * 128;
                const char* bp = (const char*)wqkv_next + (size_t)(cc * 128 + row) * 256 + off;
                #pragma unroll
                for (int j = 0; j < 8; j++) {
                    float4 v = *(const float4*)(bp + j * 16);
                    *(float4*)(Bs + row * 256 + ((off + j * 16) ^ ((row & 7) << 4))) = v;
                }
            }
            __syncthreads();
            f32x4 acc[8] = {};
            #pragma unroll
            for (int kc = 0; kc < 2; kc++) {
                #pragma unroll
                for (int kk = 0; kk < 2; kk++) {
                    int kbyte = (kc * 2 + kk) * 64 + sub * 16;
                    int rowa = w * 16 + c;
                    bf16x8 af = *(const bf16x8*)(Xs + rowa * 256 + (kbyte ^ ((rowa & 7) << 4)));
                    #pragma unroll
                    for (int n = 0; n < 8; n++) {
                        int rowb = n * 16 + c;
                        bf16x8 bf8 = *(const bf16x8*)(Bs + rowb * 256 + (kbyte ^ ((rowb & 7) << 4)));
                        acc[n] = __builtin_amdgcn_mfma_f32_16x16x32_bf16(af, bf8, acc[n], 0, 0, 0);
                    }
                }
            }
            #pragma unroll
            for (int i = 0; i < 4; i++) {
                int grow = r0 + w * 16 + sub * 4 + i;
                #pragma unroll
                for (int n = 0; n < 8; n++) {
                    int col = cc * 128 + n * 16 + c;
                    qkvb_out[(size_t)grow * 384 + col] = __float2bfloat16(acc[n][i] + bqkv_next[col]);
                }
            }
            __syncthreads();
        }
    }
}

// Fused single-pass attention on qkv[M][384] with KV-interleaved layout.
__global__ __launch_bounds__(256) void attn_fused(
    const bf16* __restrict__ qkv,
    const int* __restrict__ cnt, const u16* __restrict__ ssrc,
    bf16* __restrict__ aggout)
{
    const float S2 = 0.25f * 1.44269504088896f;   // scale/ln2
    int wid = threadIdx.x >> 6, lane = threadIdx.x & 63;
    int d = blockIdx.x * 4 + wid;
    if (d >= N_NODES) return;
    int slot = lane >> 3, h = lane & 7;

    const u32* qr = (const u32*)(qkv + (size_t)d * 384 + h * DH);
    float qf[16];
    {
        uint4 q0 = *(const uint4*)(qr);
        uint4 q1 = *(const uint4*)(qr + 4);
        qf[0]=bflo(q0.x); qf[1]=bfhi(q0.x); qf[2]=bflo(q0.y); qf[3]=bfhi(q0.y);
        qf[4]=bflo(q0.z); qf[5]=bfhi(q0.z); qf[6]=bflo(q0.w); qf[7]=bfhi(q0.w);
        qf[8]=bflo(q1.x); qf[9]=bfhi(q1.x); qf[10]=bflo(q1.y); qf[11]=bfhi(q1.y);
        qf[12]=bflo(q1.z); qf[13]=bfhi(q1.z); qf[14]=bflo(q1.w); qf[15]=bfhi(q1.w);
    }

    int deg = cnt[d];
    if (deg > CAP) deg = CAP;
    const u16* bp = ssrc + (size_t)d * CAP;
    float m2 = -INFINITY, den = 0.f;
    float acc[16] = {};

    for (int i = slot; i < deg; i += 8) {
        int s = bp[i];
        const uint4* kvp = (const uint4*)(qkv + (size_t)s * 384 + 128 + h * 32);
        uint4 k0 = kvp[0], k1 = kvp[1], v0 = kvp[2], v1 = kvp[3];
        float p = qf[0]*bflo(k0.x) + qf[1]*bfhi(k0.x)
                + qf[2]*bflo(k0.y) + qf[3]*bfhi(k0.y)
                + qf[4]*bflo(k0.z) + qf[5]*bfhi(k0.z)
                + qf[6]*bflo(k0.w) + qf[7]*bfhi(k0.w)
                + qf[8]*bflo(k1.x) + qf[9]*bfhi(k1.x)
                + qf[10]*bflo(k1.y) + qf[11]*bfhi(k1.y)
                + qf[12]*bflo(k1.z) + qf[13]*bfhi(k1.z)
                + qf[14]*bflo(k1.w) + qf[15]*bfhi(k1.w);
        float p2 = p * S2;
        float w;
        if (p2 > m2 + 8.f) {
            float f = exp2f(m2 - p2);
            den *= f;
            #pragma unroll
            for (int j = 0; j < 16; j++) acc[j] *= f;
            m2 = p2;
            w = 1.f;
        } else {
            w = exp2f(p2 - m2);
        }
        den += w;
        acc[0]  += w*bflo(v0.x); acc[1]  += w*bfhi(v0.x);
        acc[2]  += w*bflo(v0.y); acc[3]  += w*bfhi(v0.y);
        acc[4]  += w*bflo(v0.z); acc[5]  += w*bfhi(v0.z);
        acc[6]  += w*bflo(v0.w); acc[7]  += w*bfhi(v0.w);
        acc[8]  += w*bflo(v1.x); acc[9]  += w*bfhi(v1.x);
        acc[10] += w*bflo(v1.y); acc[11] += w*bfhi(v1.y);
        acc[12] += w*bflo(v1.z); acc[13] += w*bfhi(v1.z);
        acc[14] += w*bflo(v1.w); acc[15] += w*bfhi(v1.w);
    }

    #pragma unroll
    for (int o = 8; o < 64; o <<= 1) {
        float om   = __shfl_xor(m2, o);
        float oden = __shfl_xor(den, o);
        float M = fmaxf(m2, om);
        float fa = (m2 > -INFINITY) ? exp2f(m2 - M) : 0.f;
        float fb = (om > -INFINITY) ? exp2f(om - M) : 0.f;
        den = den * fa + oden * fb;
        #pragma unroll
        for (int j = 0; j < 16; j++) {
            float oa = __shfl_xor(acc[j], o);
            acc[j] = acc[j] * fa + oa * fb;
        }
        m2 = M;
    }

    float r = 1.f / (den + 1e-9f);
    float o0 = 0.f, o1 = 0.f;
    #pragma unroll
    for (int j = 0; j < 8; j++) {
        if (slot == j) { o0 = acc[2 * j]; o1 = acc[2 * j + 1]; }
    }
    bf16* op = aggout + (size_t)d * 384 + h * DH + slot * 2;
    op[0] = __float2bfloat16(o0 * r);
    op[1] = __float2bfloat16(o1 * r);
}

// merged pos+neg predictor
__global__ void predict_kernel(const float* __restrict__ h,
                               const int* __restrict__ ps, const int* __restrict__ pd,
                               const int* __restrict__ ns, const int* __restrict__ nd,
                               const float* __restrict__ Wp1, const float* __restrict__ bp1,
                               const float* __restrict__ Wp2, const float* __restrict__ bp2,
                               float* __restrict__ out)
{
    __shared__ float z[128];
    int p = blockIdx.x;
    int a, b;
    if (p < PP) { a = ps[p]; b = pd[p]; }
    else        { a = ns[p - PP]; b = nd[p - PP]; }
    int t = threadIdx.x;
    z[t]      = h[(size_t)a * D + t]      * h[(size_t)b * D + t];
    z[t + 64] = h[(size_t)a * D + t + 64] * h[(size_t)b * D + t + 64];
    __syncthreads();
    float acc = bp1[t];
    #pragma unroll 4
    for (int i = 0; i < 128; i++) acc += z[i] * Wp1[(size_t)i * 64 + t];
    acc = acc > 0.f ? acc : 0.2f * acc;
    float part = acc * Wp2[t];
    #pragma unroll
    for (int o = 32; o > 0; o >>= 1) part += __shfl_down(part, o);
    if (t == 0) out[p] = part + bp2[0];
}

extern "C" void kernel_launch(void* const* d_in, const int* in_sizes, int n_in,
                              void* d_out, int out_size, void* d_ws, size_t ws_size,
                              hipStream_t stream)
{
    const float* x       = (const float*)d_in[0];
    const int*   src     = (const int*)d_in[1];
    const int*   dst     = (const int*)d_in[2];
    const int*   pos_src = (const int*)d_in[3];
    const int*   pos_dst = (const int*)d_in[4];
    const int*   neg_src = (const int*)d_in[5];
    const int*   neg_dst = (const int*)d_in[6];
    const float* W_in = (const float*)d_in[7];
    const float* b_in = (const float*)d_in[8];
    const float* Wq = (const float*)d_in[9];
    const float* bq = (const float*)d_in[10];
    const float* Wk = (const float*)d_in[11];
    const float* bk = (const float*)d_in[12];
    const float* Wv = (const float*)d_in[13];
    const float* bv = (const float*)d_in[14];
    const float* Wo = (const float*)d_in[15];
    const float* bo = (const float*)d_in[16];
    const float* ln1g = (const float*)d_in[17];
    const float* ln1b = (const float*)d_in[18];
    const float* Wf1 = (const float*)d_in[19];
    const float* bf1 = (const float*)d_in[20];
    const float* Wf2 = (const float*)d_in[21];
    const float* bf2 = (const float*)d_in[22];
    const float* ln2g = (const float*)d_in[23];
    const float* ln2b = (const float*)d_in[24];
    const float* Wp1 = (const float*)d_in[25];
    const float* bp1 = (const float*)d_in[26];
    const float* Wp2 = (const float*)d_in[27];
    const float* bp2 = (const float*)d_in[28];

    float* out = (float*)d_out;
    float* h   = out + 2 * PP;                      // [N,D] f32 residual stream

    // workspace layout
    bf16* B    = (bf16*)d_ws;
    bf16* qkvb = B;                                 // [MPAD][384]
    int*  cnt  = (int*)(B + (size_t)MPAD * 384);    // [2][N]
    u16*  ssrc = (u16*)(cnt + 2 * N_NODES);         // [2][N*CAP]
    bf16* wtb  = (bf16*)(ssrc + (size_t)2 * N_NODES * CAP);
    bf16* win_t  = wtb;                             // 16384
    bf16* wqkv_t = wtb + 16384;                     // 2*49152 (kv-interleave perm)
    bf16* wo_t   = wtb + 16384 + 98304;             // 2*16384
    bf16* wf1_t  = wtb + 16384 + 98304 + 32768;     // 2*32768
    bf16* wf2_t  = wtb + 16384 + 98304 + 32768 + 65536; // 2*32768
    float* bqkv  = (float*)(wtb + 16384 + 98304 + 32768 + 65536 + 65536); // [L][384]
    int*  gbin_cnt = (int*)(bqkv + NLAYER * 384);   // [2][NBIN]
    u32*  gbin     = (u32*)(gbin_cnt + 2 * NBIN);   // [2][NBIN][GCAP]

    auto cdiv = [](int a, int b) { return (a + b - 1) / b; };
    const int GL = MPAD / 64;                       // 782

    // weight prep (+ gbin_cnt zero), CSR build
    prep_kernel<<<1093, 256, 0, stream>>>(W_in, Wq, Wk, Wv, Wo, Wf1, Wf2, bq, bk, bv,
                                          win_t, wqkv_t, wo_t, wf1_t, wf2_t, bqkv, gbin_cnt);
    bin_kernel<<<dim3(cdiv(NE, CHUNK), 2), 256, 0, stream>>>(dst, src, gbin, gbin_cnt);
    expand_kernel<<<dim3(NBIN, 2), 256, 0, stream>>>(gbin, gbin_cnt, cnt, ssrc);

    // head: h = x@W_in + b_in ; qkv0
    head_fused<<<GL, 256, 0, stream>>>(x, win_t, b_in, wqkv_t, bqkv, h, qkvb);

    for (int l = 0; l < NLAYER; l++) {
        attn_fused<<<cdiv(N_NODES, 4), 256, 0, stream>>>(qkvb, cnt + l * N_NODES,
                                                         ssrc + (size_t)l * N_NODES * CAP, qkvb);
        const bf16* wnext  = (l + 1 < NLAYER) ? (wqkv_t + (l + 1) * 49152) : nullptr;
        const float* bnext = (l + 1 < NLAYER) ? (bqkv + (l + 1) * 384) : nullptr;
        tail_fused<<<GL, 256, 0, stream>>>(qkvb, wo_t + l * 16384, bo + l * D,
                                           ln1g + l * D, ln1b + l * D,
                                           wf1_t + l * 32768, bf1 + l * FF,
                                           wf2_t + l * 32768, bf2 + l * D,
                                           ln2g + l * D, ln2b + l * D, h,
                                           wnext, bnext, qkvb);
    }

    predict_kernel<<<2 * PP, 64, 0, stream>>>(h, pos_src, pos_dst, neg_src, neg_dst,
                                              Wp1, bp1, Wp2, bp2, out);
}

// Round 17
// 349.578 us; speedup vs baseline: 1.1640x; 1.1640x over previous
//
#include <hip/hip_runtime.h>
#include <hip/hip_bf16.h>
#include <math.h>

#define N_NODES 50000
#define NE      800000
#define D       128
#define H       8
#define DH      16
#define NLAYER  2
#define IN_F    128
#define PP      8192
#define FF      256
#define MPAD    50048   // 391 * 128 = 782 * 64
#define CAP     96      // bucket capacity (mean deg 16; P(>=96)~1e-40)
#define NBIN    196     // bins of 256 nodes: bin = d >> 8
#define BCAP    48      // per-chunk per-bin LDS cap
#define GCAP    4608    // per-bin global cap
#define CHUNK   2048    // edges per phase-1 block

typedef short  bf16x8 __attribute__((ext_vector_type(8)));
typedef float  f32x4  __attribute__((ext_vector_type(4)));
typedef __hip_bfloat16 bf16;
typedef unsigned short u16;
typedef unsigned int   u32;

__device__ __forceinline__ float bflo(u32 u) { return __uint_as_float(u << 16); }
__device__ __forceinline__ float bfhi(u32 u) { return __uint_as_float(u & 0xffff0000u); }
__device__ __forceinline__ u16 bfbits(float f) { bf16 t = __float2bfloat16(f); return *(u16*)&t; }

// Phase 1: bin edges by dst>>8 via LDS, flush dense appends to per-bin global arrays.
__global__ __launch_bounds__(256) void bin_kernel(
    const int* __restrict__ dst, const int* __restrict__ src,
    u32* __restrict__ gbin, int* __restrict__ gbin_cnt)
{
    __shared__ u32 ent[NBIN * BCAP];
    __shared__ int bcnt[NBIN];
    const int t = threadIdx.x, l = blockIdx.y;
    const int base = blockIdx.x * CHUNK;
    if (t < NBIN) bcnt[t] = 0;
    __syncthreads();
    #pragma unroll
    for (int j = 0; j < CHUNK / 256; j++) {
        int e = base + j * 256 + t;
        if (e < NE) {
            int d = dst[(size_t)l * NE + e];
            int s = src[(size_t)l * NE + e];
            int bin = d >> 8;
            int slot = atomicAdd(&bcnt[bin], 1);
            if (slot < BCAP) ent[bin * BCAP + slot] = ((u32)s << 16) | (u32)(d & 255);
        }
    }
    __syncthreads();
    if (t < NBIN) {
        int c = bcnt[t]; if (c > BCAP) c = BCAP;
        if (c > 0) {
            int gb = atomicAdd(&gbin_cnt[l * NBIN + t], c);
            u32* gp = gbin + ((size_t)l * NBIN + t) * GCAP;
            for (int i = 0; i < c; i++)
                if (gb + i < GCAP) gp[gb + i] = ent[t * BCAP + i];
        }
    }
}

// Phase 2: per (bin, layer) block expands packed edges into CAP-buckets via LDS counters.
__global__ __launch_bounds__(256) void expand_kernel(
    const u32* __restrict__ gbin, const int* __restrict__ gbin_cnt,
    int* __restrict__ cnt, u16* __restrict__ ssrc)
{
    __shared__ int lcnt[256];
    const int t = threadIdx.x, b = blockIdx.x, l = blockIdx.y;
    lcnt[t] = 0;
    __syncthreads();
    int n = gbin_cnt[l * NBIN + b]; if (n > GCAP) n = GCAP;
    const u32* gp = gbin + ((size_t)l * NBIN + b) * GCAP;
    for (int i = t; i < n; i += 256) {
        u32 u = gp[i];
        int dl = (int)(u & 255);
        int pos = atomicAdd(&lcnt[dl], 1);
        if (pos < CAP) {
            int d = (b << 8) + dl;
            ssrc[((size_t)l * N_NODES + d) * CAP + pos] = (u16)(u >> 16);
        }
    }
    __syncthreads();
    int d = (b << 8) + t;
    if (d < N_NODES) cnt[l * N_NODES + d] = lcnt[t];
}

__global__ void xb_kernel(const float* __restrict__ x, bf16* __restrict__ xb) {
    int id = blockIdx.x * blockDim.x + threadIdx.x;
    if (id >= MPAD * IN_F) return;
    int r = id / IN_F;
    xb[id] = __float2bfloat16(r < N_NODES ? x[id] : 0.f);
}

// One-shot weight prep: transpose+bf16 all weights, KV-interleaved QKV perm, bias cat,
// gbin_cnt zeroing (replaces the memset launch).
__global__ void prep_kernel(const float* __restrict__ W_in,
                            const float* __restrict__ Wq, const float* __restrict__ Wk,
                            const float* __restrict__ Wv, const float* __restrict__ Wo,
                            const float* __restrict__ Wf1, const float* __restrict__ Wf2,
                            const float* __restrict__ bq, const float* __restrict__ bk,
                            const float* __restrict__ bv,
                            bf16* __restrict__ win_t, bf16* __restrict__ wqkv_t,
                            bf16* __restrict__ wo_t, bf16* __restrict__ wf1_t,
                            bf16* __restrict__ wf2_t, float* __restrict__ bqkv,
                            int* __restrict__ gbin_cnt)
{
    int id = blockIdx.x * blockDim.x + threadIdx.x;
    if (id < 16384) {
        int n = id >> 7, k = id & 127;
        win_t[id] = __float2bfloat16(W_in[k * 128 + n]);
        return;
    }
    id -= 16384;
    if (id < NLAYER * 49152) {           // QKV, rows permuted for kv-interleave
        int l = id / 49152, j = id % 49152;
        int r = j >> 7, k = j & 127;
        const float* Ws; int col;
        if (r < 128) { Ws = Wq; col = r; }
        else {
            int u = r - 128, hh = u >> 5, w = u & 31;
            if (w < 16) { Ws = Wk; col = hh * 16 + w; }
            else        { Ws = Wv; col = hh * 16 + w - 16; }
        }
        wqkv_t[(size_t)l * 49152 + j] = __float2bfloat16(Ws[(size_t)l * 16384 + k * 128 + col]);
        return;
    }
    id -= NLAYER * 49152;
    if (id < NLAYER * 16384) {
        int l = id / 16384, j = id % 16384;
        int n = j >> 7, k = j & 127;
        wo_t[id] = __float2bfloat16(Wo[(size_t)l * 16384 + k * 128 + n]);
        return;
    }
    id -= NLAYER * 16384;
    if (id < NLAYER * 32768) {           // wf1: [256][128] from [128][256]
        int l = id / 32768, j = id % 32768;
        int n = j >> 7, k = j & 127;
        wf1_t[id] = __float2bfloat16(Wf1[(size_t)l * 32768 + k * 256 + n]);
        return;
    }
    id -= NLAYER * 32768;
    if (id < NLAYER * 32768) {           // wf2: [128][256] from [256][128]
        int l = id / 32768, j = id % 32768;
        int n = j >> 8, k = j & 255;
        wf2_t[id] = __float2bfloat16(Wf2[(size_t)l * 32768 + k * 128 + n]);
        return;
    }
    id -= NLAYER * 32768;
    if (id < NLAYER * 384) {             // bias cat with same perm
        int l = id / 384, r = id % 384;
        float v;
        if (r < 128) v = bq[l * 128 + r];
        else {
            int u = r - 128, hh = u >> 5, w = u & 31;
            v = (w < 16) ? bk[l * 128 + hh * 16 + w] : bv[l * 128 + hh * 16 + w - 16];
        }
        bqkv[l * 384 + r] = v;
        return;
    }
    id -= NLAYER * 384;
    if (id < 2 * NBIN) gbin_cnt[id] = 0;
}

// C[M,Nc] = act(A[M,K] @ W + bias); A bf16 [*,lda], Wt bf16 [Nc,K] transposed.
__global__ __launch_bounds__(256) void gemm_mfma(
    const bf16* __restrict__ A, const bf16* __restrict__ Wt,
    const float* __restrict__ bias,
    float* __restrict__ Cf, bf16* __restrict__ Cb,
    int Mvalid, int K, int Nc, int lda, int relu)
{
    __shared__ float4 As4[1024];
    __shared__ float4 Bs4[1024];
    char* As = (char*)As4;
    char* Bs = (char*)Bs4;
    const int t = threadIdx.x;
    const int wave = t >> 6, lane = t & 63;
    const int wr = wave >> 1, wc = wave & 1;
    const int r0 = blockIdx.x * 128, c0 = blockIdx.y * 128;

    f32x4 acc[4][4] = {};

    const int lrow   = t >> 3;
    const int lcol16 = (t & 7) * 16;

    for (int k0 = 0; k0 < K; k0 += 64) {
        #pragma unroll
        for (int p = 0; p < 4; p++) {
            int row = p * 32 + lrow;
            float4 av = *(const float4*)((const char*)(A  + (size_t)(r0 + row) * lda + k0) + lcol16);
            float4 bv = *(const float4*)((const char*)(Wt + (size_t)(c0 + row) * K + k0) + lcol16);
            int sw = lcol16 ^ ((row & 7) << 4);
            *(float4*)(As + row * 128 + sw) = av;
            *(float4*)(Bs + row * 128 + sw) = bv;
        }
        __syncthreads();
        #pragma unroll
        for (int kk = 0; kk < 2; kk++) {
            bf16x8 af[4], bfr[4];
            int kbyte = kk * 64 + (lane >> 4) * 16;
            #pragma unroll
            for (int m = 0; m < 4; m++) {
                int rowa = wr * 64 + m * 16 + (lane & 15);
                af[m]  = *(const bf16x8*)(As + rowa * 128 + (kbyte ^ ((rowa & 7) << 4)));
                int rowb = wc * 64 + m * 16 + (lane & 15);
                bfr[m] = *(const bf16x8*)(Bs + rowb * 128 + (kbyte ^ ((rowb & 7) << 4)));
            }
            #pragma unroll
            for (int m = 0; m < 4; m++)
                #pragma unroll
                for (int n = 0; n < 4; n++)
                    acc[m][n] = __builtin_amdgcn_mfma_f32_16x16x32_bf16(af[m], bfr[n], acc[m][n], 0, 0, 0);
        }
        __syncthreads();
    }

    const int colbase = c0 + wc * 64 + (lane & 15);
    const int rowbase = r0 + wr * 64 + ((lane >> 4) << 2);
    #pragma unroll
    for (int n = 0; n < 4; n++) {
        int col = colbase + n * 16;
        float bsv = bias[col];
        #pragma unroll
        for (int m = 0; m < 4; m++) {
            #pragma unroll
            for (int i = 0; i < 4; i++) {
                int row = rowbase + m * 16 + i;
                if (row < Mvalid) {
                    float v = acc[m][n][i] + bsv;
                    if (relu) v = fmaxf(v, 0.f);
                    if (Cf) Cf[(size_t)row * Nc + col] = v;
                    if (Cb) Cb[(size_t)row * Nc + col] = __float2bfloat16(v);
                }
            }
        }
    }
}

// Fused layer tail: h = LN2( LN1(h + agg@Wo + bo) + FFN(LN1(...)) ).
// 48KB LDS (3 blocks/CU): FF1/FF2 interleaved per 128-hidden half; weights staged
// in 16KB sub-chunks. Per-element K-accumulation order identical to the R14
// gemm_ln+ffn pair -> bit-identical results.
__global__ __launch_bounds__(256) void tail_fused(
    const bf16* __restrict__ qkv,    // agg in q-section, lda=384
    const bf16* __restrict__ wo_t,   // [128][128]
    const float* __restrict__ bo,
    const float* __restrict__ g1, const float* __restrict__ be1,
    const bf16* __restrict__ Wf1t,   // [256][128]
    const float* __restrict__ b1,
    const bf16* __restrict__ Wf2t,   // [128][256]
    const float* __restrict__ b2,
    const float* __restrict__ g2, const float* __restrict__ be2,
    float* __restrict__ h, bf16* __restrict__ hb)
{
    __shared__ char lds[49152];
    char* AsA = lds;                 // part1: 64 x 128B A-chunk (overlaps Ah1)
    char* Ah1 = lds;                 // 64 x 256B h1 (bf16, swizzled)
    char* Xs  = lds + 16384;         // 64 x 256B X-half (bf16, swizzled)
    char* Bs  = lds + 32768;         // 16KB weight chunk buffer
    const int t = threadIdx.x;
    const int w = t >> 6, lane = t & 63;
    const int r0 = blockIdx.x * 64;
    const int c = lane & 15, sub = lane >> 4;

    // ---- part 1: T = agg @ Wo (K=128 in 2 chunks of 64) ----
    f32x4 acc0[8] = {};
    #pragma unroll
    for (int k0 = 0; k0 < 128; k0 += 64) {
        {
            int row = t >> 2;
            int c16 = (t & 3) * 32;
            const char* ap = (const char*)(qkv + (size_t)(r0 + row) * 384 + k0);
            float4 a0 = *(const float4*)(ap + c16);
            float4 a1 = *(const float4*)(ap + c16 + 16);
            *(float4*)(AsA + row * 128 + ((c16)      ^ ((row & 7) << 4))) = a0;
            *(float4*)(AsA + row * 128 + ((c16 + 16) ^ ((row & 7) << 4))) = a1;
        }
        {
            int row = t >> 1;
            int c16 = (t & 1) * 64;
            const char* bp = (const char*)(wo_t + (size_t)row * 128 + k0);
            #pragma unroll
            for (int j = 0; j < 4; j++) {
                float4 b = *(const float4*)(bp + c16 + j * 16);
                *(float4*)(Bs + row * 128 + ((c16 + j * 16) ^ ((row & 7) << 4))) = b;
            }
        }
        __syncthreads();
        #pragma unroll
        for (int kk = 0; kk < 2; kk++) {
            int kbyte = kk * 64 + sub * 16;
            int rowa = w * 16 + c;
            bf16x8 af = *(const bf16x8*)(AsA + rowa * 128 + (kbyte ^ ((rowa & 7) << 4)));
            #pragma unroll
            for (int n = 0; n < 8; n++) {
                int rowb = n * 16 + c;
                bf16x8 bf8 = *(const bf16x8*)(Bs + rowb * 128 + (kbyte ^ ((rowb & 7) << 4)));
                acc0[n] = __builtin_amdgcn_mfma_f32_16x16x32_bf16(af, bf8, acc0[n], 0, 0, 0);
            }
        }
        __syncthreads();
    }

    // ---- LN1: h1 in regs + Ah1 in LDS (bf16) ----
    float h1v[8][4];
    {
        float bsv[8], gv[8], bev[8];
        #pragma unroll
        for (int n = 0; n < 8; n++) {
            int col = n * 16 + c;
            bsv[n] = bo[col]; gv[n] = g1[col]; bev[n] = be1[col];
        }
        #pragma unroll
        for (int i = 0; i < 4; i++) {
            int row = r0 + w * 16 + sub * 4 + i;
            bool ok = row < N_NODES;
            float x[8];
            float s = 0.f;
            #pragma unroll
            for (int n = 0; n < 8; n++) {
                float res = ok ? h[(size_t)row * D + n * 16 + c] : 0.f;
                x[n] = res + acc0[n][i] + bsv[n];
                s += x[n];
            }
            s += __shfl_xor(s, 1); s += __shfl_xor(s, 2);
            s += __shfl_xor(s, 4); s += __shfl_xor(s, 8);
            float mean = s * (1.f / 128.f);
            float v = 0.f;
            #pragma unroll
            for (int n = 0; n < 8; n++) { float dd = x[n] - mean; v += dd * dd; }
            v += __shfl_xor(v, 1); v += __shfl_xor(v, 2);
            v += __shfl_xor(v, 4); v += __shfl_xor(v, 8);
            float rstd = rsqrtf(v * (1.f / 128.f) + 1e-5f);
            int lrow = w * 16 + sub * 4 + i;
            #pragma unroll
            for (int n = 0; n < 8; n++) {
                float o = (x[n] - mean) * rstd * gv[n] + bev[n];
                h1v[n][i] = o;
                int byte = (n * 16 + c) * 2;
                int addr = lrow * 256 + ((byte & ~15) ^ ((lrow & 7) << 4)) + (byte & 15);
                *(u16*)(Ah1 + addr) = bfbits(o);
            }
        }
    }
    __syncthreads();

    // ---- parts 2+3 interleaved per 128-hidden half (Xs 16KB, Bs 16KB) ----
    f32x4 acc2[8] = {};
    #pragma unroll
    for (int xh = 0; xh < 2; xh++) {
        // FF1 for hidden cols [xh*128, xh*128+128)
        f32x4 acc1[8] = {};
        #pragma unroll
        for (int kc = 0; kc < 2; kc++) {
            {   // stage Wf1 rows [xh*128, +128), K-chunk kc: 128 rows x 128B
                int row = t >> 1;
                int off = (t & 1) * 64;
                const char* bp = (const char*)Wf1t + (size_t)(xh * 128 + row) * 256 + kc * 128 + off;
                #pragma unroll
                for (int j = 0; j < 4; j++) {
                    float4 v = *(const float4*)(bp + j * 16);
                    *(float4*)(Bs + row * 128 + ((off + j * 16) ^ ((row & 7) << 4))) = v;
                }
            }
            __syncthreads();
            #pragma unroll
            for (int kkl = 0; kkl < 2; kkl++) {
                int abyte = (kc * 2 + kkl) * 64 + sub * 16;
                int rowa = w * 16 + c;
                bf16x8 af = *(const bf16x8*)(Ah1 + rowa * 256 + (abyte ^ ((rowa & 7) << 4)));
                int bbyte = kkl * 64 + sub * 16;
                #pragma unroll
                for (int n = 0; n < 8; n++) {
                    int rowb = n * 16 + c;
                    bf16x8 bf8 = *(const bf16x8*)(Bs + rowb * 128 + (bbyte ^ ((rowb & 7) << 4)));
                    acc1[n] = __builtin_amdgcn_mfma_f32_16x16x32_bf16(af, bf8, acc1[n], 0, 0, 0);
                }
            }
            __syncthreads();
        }
        // bias + relu + X-half to Xs (64 x 256B, swizzled)
        #pragma unroll
        for (int n = 0; n < 8; n++) {
            float bs = b1[xh * 128 + n * 16 + c];
            #pragma unroll
            for (int i = 0; i < 4; i++) {
                int row = w * 16 + sub * 4 + i;
                float v = fmaxf(acc1[n][i] + bs, 0.f);
                int byte = (n * 16 + c) * 2;
                int addr = row * 256 + ((byte & ~15) ^ ((row & 7) << 4)) + (byte & 15);
                *(u16*)(Xs + addr) = bfbits(v);
            }
        }
        __syncthreads();
        // FF2 partial: K-chunk xh, output split in two 64-col halves
        #pragma unroll
        for (int oh = 0; oh < 2; oh++) {
            {   // stage Wf2 rows [oh*64, +64), K-bytes [xh*256, +256): 64 rows x 256B
                int row = t >> 2;
                int off = (t & 3) * 64;
                const char* bp = (const char*)Wf2t + (size_t)(oh * 64 + row) * 512 + xh * 256 + off;
                #pragma unroll
                for (int j = 0; j < 4; j++) {
                    float4 v = *(const float4*)(bp + j * 16);
                    *(float4*)(Bs + row * 256 + ((off + j * 16) ^ ((row & 7) << 4))) = v;
                }
            }
            __syncthreads();
            #pragma unroll
            for (int kkl = 0; kkl < 4; kkl++) {
                int xbyte = kkl * 64 + sub * 16;
                int rowa = w * 16 + c;
                bf16x8 af = *(const bf16x8*)(Xs + rowa * 256 + (xbyte ^ ((rowa & 7) << 4)));
                #pragma unroll
                for (int n = 0; n < 4; n++) {
                    int rowb = n * 16 + c;
                    bf16x8 bf8 = *(const bf16x8*)(Bs + rowb * 256 + (xbyte ^ ((rowb & 7) << 4)));
                    acc2[oh * 4 + n] = __builtin_amdgcn_mfma_f32_16x16x32_bf16(af, bf8, acc2[oh * 4 + n], 0, 0, 0);
                }
            }
            __syncthreads();
        }
    }

    // ---- LN2 epilogue (acc2[m] <-> col m*16+c, same mapping as before) ----
    {
        float bsv[8], gv[8], bev[8];
        #pragma unroll
        for (int n = 0; n < 8; n++) {
            int col = n * 16 + c;
            bsv[n] = b2[col]; gv[n] = g2[col]; bev[n] = be2[col];
        }
        #pragma unroll
        for (int i = 0; i < 4; i++) {
            int row = r0 + w * 16 + sub * 4 + i;
            bool ok = row < N_NODES;
            float x[8];
            float s = 0.f;
            #pragma unroll
            for (int n = 0; n < 8; n++) {
                x[n] = h1v[n][i] + acc2[n][i] + bsv[n];
                s += x[n];
            }
            s += __shfl_xor(s, 1); s += __shfl_xor(s, 2);
            s += __shfl_xor(s, 4); s += __shfl_xor(s, 8);
            float mean = s * (1.f / 128.f);
            float v = 0.f;
            #pragma unroll
            for (int n = 0; n < 8; n++) { float dd = x[n] - mean; v += dd * dd; }
            v += __shfl_xor(v, 1); v += __shfl_xor(v, 2);
            v += __shfl_xor(v, 4); v += __shfl_xor(v, 8);
            float rstd = rsqrtf(v * (1.f / 128.f) + 1e-5f);
            if (ok) {
                #pragma unroll
                for (int n = 0; n < 8; n++) {
                    float o = (x[n] - mean) * rstd * gv[n] + bev[n];
                    h [(size_t)row * D + n * 16 + c] = o;
                    hb[(size_t)row * D + n * 16 + c] = __float2bfloat16(o);
                }
            }
        }
    }
}

// Fused single-pass attention on qkv[M][384] with KV-interleaved layout.
__global__ __launch_bounds__(256) void attn_fused(
    const bf16* __restrict__ qkv,
    const int* __restrict__ cnt, const u16* __restrict__ ssrc,
    bf16* __restrict__ aggout)
{
    const float S2 = 0.25f * 1.44269504088896f;   // scale/ln2
    int wid = threadIdx.x >> 6, lane = threadIdx.x & 63;
    int d = blockIdx.x * 4 + wid;
    if (d >= N_NODES) return;
    int slot = lane >> 3, h = lane & 7;

    const u32* qr = (const u32*)(qkv + (size_t)d * 384 + h * DH);
    float qf[16];
    {
        uint4 q0 = *(const uint4*)(qr);
        uint4 q1 = *(const uint4*)(qr + 4);
        qf[0]=bflo(q0.x); qf[1]=bfhi(q0.x); qf[2]=bflo(q0.y); qf[3]=bfhi(q0.y);
        qf[4]=bflo(q0.z); qf[5]=bfhi(q0.z); qf[6]=bflo(q0.w); qf[7]=bfhi(q0.w);
        qf[8]=bflo(q1.x); qf[9]=bfhi(q1.x); qf[10]=bflo(q1.y); qf[11]=bfhi(q1.y);
        qf[12]=bflo(q1.z); qf[13]=bfhi(q1.z); qf[14]=bflo(q1.w); qf[15]=bfhi(q1.w);
    }

    int deg = cnt[d];
    if (deg > CAP) deg = CAP;
    const u16* bp = ssrc + (size_t)d * CAP;
    float m2 = -INFINITY, den = 0.f;
    float acc[16] = {};

    for (int i = slot; i < deg; i += 8) {
        int s = bp[i];
        const uint4* kvp = (const uint4*)(qkv + (size_t)s * 384 + 128 + h * 32);
        uint4 k0 = kvp[0], k1 = kvp[1], v0 = kvp[2], v1 = kvp[3];
        float p = qf[0]*bflo(k0.x) + qf[1]*bfhi(k0.x)
                + qf[2]*bflo(k0.y) + qf[3]*bfhi(k0.y)
                + qf[4]*bflo(k0.z) + qf[5]*bfhi(k0.z)
                + qf[6]*bflo(k0.w) + qf[7]*bfhi(k0.w)
                + qf[8]*bflo(k1.x) + qf[9]*bfhi(k1.x)
                + qf[10]*bflo(k1.y) + qf[11]*bfhi(k1.y)
                + qf[12]*bflo(k1.z) + qf[13]*bfhi(k1.z)
                + qf[14]*bflo(k1.w) + qf[15]*bfhi(k1.w);
        float p2 = p * S2;
        float w;
        if (p2 > m2 + 8.f) {
            float f = exp2f(m2 - p2);
            den *= f;
            #pragma unroll
            for (int j = 0; j < 16; j++) acc[j] *= f;
            m2 = p2;
            w = 1.f;
        } else {
            w = exp2f(p2 - m2);
        }
        den += w;
        acc[0]  += w*bflo(v0.x); acc[1]  += w*bfhi(v0.x);
        acc[2]  += w*bflo(v0.y); acc[3]  += w*bfhi(v0.y);
        acc[4]  += w*bflo(v0.z); acc[5]  += w*bfhi(v0.z);
        acc[6]  += w*bflo(v0.w); acc[7]  += w*bfhi(v0.w);
        acc[8]  += w*bflo(v1.x); acc[9]  += w*bfhi(v1.x);
        acc[10] += w*bflo(v1.y); acc[11] += w*bfhi(v1.y);
        acc[12] += w*bflo(v1.z); acc[13] += w*bfhi(v1.z);
        acc[14] += w*bflo(v1.w); acc[15] += w*bfhi(v1.w);
    }

    #pragma unroll
    for (int o = 8; o < 64; o <<= 1) {
        float om   = __shfl_xor(m2, o);
        float oden = __shfl_xor(den, o);
        float M = fmaxf(m2, om);
        float fa = (m2 > -INFINITY) ? exp2f(m2 - M) : 0.f;
        float fb = (om > -INFINITY) ? exp2f(om - M) : 0.f;
        den = den * fa + oden * fb;
        #pragma unroll
        for (int j = 0; j < 16; j++) {
            float oa = __shfl_xor(acc[j], o);
            acc[j] = acc[j] * fa + oa * fb;
        }
        m2 = M;
    }

    float r = 1.f / (den + 1e-9f);
    float o0 = 0.f, o1 = 0.f;
    #pragma unroll
    for (int j = 0; j < 8; j++) {
        if (slot == j) { o0 = acc[2 * j]; o1 = acc[2 * j + 1]; }
    }
    bf16* op = aggout + (size_t)d * 384 + h * DH + slot * 2;
    op[0] = __float2bfloat16(o0 * r);
    op[1] = __float2bfloat16(o1 * r);
}

// merged pos+neg predictor
__global__ void predict_kernel(const float* __restrict__ h,
                               const int* __restrict__ ps, const int* __restrict__ pd,
                               const int* __restrict__ ns, const int* __restrict__ nd,
                               const float* __restrict__ Wp1, const float* __restrict__ bp1,
                               const float* __restrict__ Wp2, const float* __restrict__ bp2,
                               float* __restrict__ out)
{
    __shared__ float z[128];
    int p = blockIdx.x;
    int a, b;
    if (p < PP) { a = ps[p]; b = pd[p]; }
    else        { a = ns[p - PP]; b = nd[p - PP]; }
    int t = threadIdx.x;
    z[t]      = h[(size_t)a * D + t]      * h[(size_t)b * D + t];
    z[t + 64] = h[(size_t)a * D + t + 64] * h[(size_t)b * D + t + 64];
    __syncthreads();
    float acc = bp1[t];
    #pragma unroll 4
    for (int i = 0; i < 128; i++) acc += z[i] * Wp1[(size_t)i * 64 + t];
    acc = acc > 0.f ? acc : 0.2f * acc;
    float part = acc * Wp2[t];
    #pragma unroll
    for (int o = 32; o > 0; o >>= 1) part += __shfl_down(part, o);
    if (t == 0) out[p] = part + bp2[0];
}

extern "C" void kernel_launch(void* const* d_in, const int* in_sizes, int n_in,
                              void* d_out, int out_size, void* d_ws, size_t ws_size,
                              hipStream_t stream)
{
    const float* x       = (const float*)d_in[0];
    const int*   src     = (const int*)d_in[1];
    const int*   dst     = (const int*)d_in[2];
    const int*   pos_src = (const int*)d_in[3];
    const int*   pos_dst = (const int*)d_in[4];
    const int*   neg_src = (const int*)d_in[5];
    const int*   neg_dst = (const int*)d_in[6];
    const float* W_in = (const float*)d_in[7];
    const float* b_in = (const float*)d_in[8];
    const float* Wq = (const float*)d_in[9];
    const float* bq = (const float*)d_in[10];
    const float* Wk = (const float*)d_in[11];
    const float* bk = (const float*)d_in[12];
    const float* Wv = (const float*)d_in[13];
    const float* bv = (const float*)d_in[14];
    const float* Wo = (const float*)d_in[15];
    const float* bo = (const float*)d_in[16];
    const float* ln1g = (const float*)d_in[17];
    const float* ln1b = (const float*)d_in[18];
    const float* Wf1 = (const float*)d_in[19];
    const float* bf1 = (const float*)d_in[20];
    const float* Wf2 = (const float*)d_in[21];
    const float* bf2 = (const float*)d_in[22];
    const float* ln2g = (const float*)d_in[23];
    const float* ln2b = (const float*)d_in[24];
    const float* Wp1 = (const float*)d_in[25];
    const float* bp1 = (const float*)d_in[26];
    const float* Wp2 = (const float*)d_in[27];
    const float* bp2 = (const float*)d_in[28];

    float* out = (float*)d_out;
    float* h   = out + 2 * PP;                      // [N,D] f32 residual stream

    // workspace layout
    bf16* B    = (bf16*)d_ws;
    bf16* qkvb = B;                                 // [MPAD][384]
    bf16* xb   = B;                                 // overlay [MPAD][128]
    bf16* hb   = B + (size_t)MPAD * 384;            // [MPAD][128]
    int*  cnt  = (int*)(hb + (size_t)MPAD * 128);   // [2][N]
    u16*  ssrc = (u16*)(cnt + 2 * N_NODES);         // [2][N*CAP]
    bf16* wtb  = (bf16*)(ssrc + (size_t)2 * N_NODES * CAP);
    bf16* win_t  = wtb;                             // 16384
    bf16* wqkv_t = wtb + 16384;                     // 2*49152 (kv-interleave perm)
    bf16* wo_t   = wtb + 16384 + 98304;             // 2*16384
    bf16* wf1_t  = wtb + 16384 + 98304 + 32768;     // 2*32768
    bf16* wf2_t  = wtb + 16384 + 98304 + 32768 + 65536; // 2*32768
    float* bqkv  = (float*)(wtb + 16384 + 98304 + 32768 + 65536 + 65536); // [L][384]
    int*  gbin_cnt = (int*)(bqkv + NLAYER * 384);   // [2][NBIN]
    u32*  gbin     = (u32*)(gbin_cnt + 2 * NBIN);   // [2][NBIN][GCAP]

    auto cdiv = [](int a, int b) { return (a + b - 1) / b; };
    const int GX = MPAD / 128;                      // 391
    const int GL = MPAD / 64;                       // 782

    // one-time converts (prep also zeroes gbin_cnt)
    xb_kernel<<<cdiv(MPAD * IN_F, 256), 256, 0, stream>>>(x, xb);
    prep_kernel<<<1093, 256, 0, stream>>>(W_in, Wq, Wk, Wv, Wo, Wf1, Wf2, bq, bk, bv,
                                          win_t, wqkv_t, wo_t, wf1_t, wf2_t, bqkv, gbin_cnt);

    // CSR build: bin -> expand
    bin_kernel<<<dim3(cdiv(NE, CHUNK), 2), 256, 0, stream>>>(dst, src, gbin, gbin_cnt);
    expand_kernel<<<dim3(NBIN, 2), 256, 0, stream>>>(gbin, gbin_cnt, cnt, ssrc);

    // h = x @ W_in + b_in
    gemm_mfma<<<dim3(GX, 1), 256, 0, stream>>>(xb, win_t, b_in, h, hb, N_NODES, 128, 128, 128, 0);

    for (int l = 0; l < NLAYER; l++) {
        gemm_mfma<<<dim3(GX, 3), 256, 0, stream>>>(hb, wqkv_t + l * 49152, bqkv + l * 384,
                                                   nullptr, qkvb, N_NODES, 128, 384, 128, 0);

        attn_fused<<<cdiv(N_NODES, 4), 256, 0, stream>>>(qkvb, cnt + l * N_NODES,
                                                         ssrc + (size_t)l * N_NODES * CAP, qkvb);

        tail_fused<<<GL, 256, 0, stream>>>(qkvb, wo_t + l * 16384, bo + l * D,
                                           ln1g + l * D, ln1b + l * D,
                                           wf1_t + l * 32768, bf1 + l * FF,
                                           wf2_t + l * 32768, bf2 + l * D,
                                           ln2g + l * D, ln2b + l * D, h, hb);
    }

    predict_kernel<<<2 * PP, 64, 0, stream>>>(h, pos_src, pos_dst, neg_src, neg_dst,
                                              Wp1, bp1, Wp2, bp2, out);
}

// Round 18
// 340.327 us; speedup vs baseline: 1.1956x; 1.0272x over previous
//
#include <hip/hip_runtime.h>
#include <hip/hip_bf16.h>
#include <math.h>

#define N_NODES 50000
#define NE      800000
#define D       128
#define H       8
#define DH      16
#define NLAYER  2
#define IN_F    128
#define PP      8192
#define FF      256
#define MPAD    50048   // 391 * 128 = 782 * 64
#define CAP     96      // bucket capacity (mean deg 16; P(>=96)~1e-40)
#define NBIN    196     // bins of 256 nodes: bin = d >> 8
#define BCAP    48      // per-chunk per-bin LDS cap
#define GCAP    4608    // per-bin global cap
#define CHUNK   2048    // edges per phase-1 block

typedef short  bf16x8 __attribute__((ext_vector_type(8)));
typedef float  f32x4  __attribute__((ext_vector_type(4)));
typedef __hip_bfloat16 bf16;
typedef unsigned short u16;
typedef unsigned int   u32;

__device__ __forceinline__ float bflo(u32 u) { return __uint_as_float(u << 16); }
__device__ __forceinline__ float bfhi(u32 u) { return __uint_as_float(u & 0xffff0000u); }
__device__ __forceinline__ u16 bfbits(float f) { bf16 t = __float2bfloat16(f); return *(u16*)&t; }

// Phase 1: bin edges by dst>>8 via LDS, flush dense appends to per-bin global arrays.
__global__ __launch_bounds__(256) void bin_kernel(
    const int* __restrict__ dst, const int* __restrict__ src,
    u32* __restrict__ gbin, int* __restrict__ gbin_cnt)
{
    __shared__ u32 ent[NBIN * BCAP];
    __shared__ int bcnt[NBIN];
    const int t = threadIdx.x, l = blockIdx.y;
    const int base = blockIdx.x * CHUNK;
    if (t < NBIN) bcnt[t] = 0;
    __syncthreads();
    #pragma unroll
    for (int j = 0; j < CHUNK / 256; j++) {
        int e = base + j * 256 + t;
        if (e < NE) {
            int d = dst[(size_t)l * NE + e];
            int s = src[(size_t)l * NE + e];
            int bin = d >> 8;
            int slot = atomicAdd(&bcnt[bin], 1);
            if (slot < BCAP) ent[bin * BCAP + slot] = ((u32)s << 16) | (u32)(d & 255);
        }
    }
    __syncthreads();
    if (t < NBIN) {
        int c = bcnt[t]; if (c > BCAP) c = BCAP;
        if (c > 0) {
            int gb = atomicAdd(&gbin_cnt[l * NBIN + t], c);
            u32* gp = gbin + ((size_t)l * NBIN + t) * GCAP;
            for (int i = 0; i < c; i++)
                if (gb + i < GCAP) gp[gb + i] = ent[t * BCAP + i];
        }
    }
}

// Phase 2: per (bin, layer) block expands packed edges into CAP-buckets via LDS counters.
__global__ __launch_bounds__(256) void expand_kernel(
    const u32* __restrict__ gbin, const int* __restrict__ gbin_cnt,
    int* __restrict__ cnt, u16* __restrict__ ssrc)
{
    __shared__ int lcnt[256];
    const int t = threadIdx.x, b = blockIdx.x, l = blockIdx.y;
    lcnt[t] = 0;
    __syncthreads();
    int n = gbin_cnt[l * NBIN + b]; if (n > GCAP) n = GCAP;
    const u32* gp = gbin + ((size_t)l * NBIN + b) * GCAP;
    for (int i = t; i < n; i += 256) {
        u32 u = gp[i];
        int dl = (int)(u & 255);
        int pos = atomicAdd(&lcnt[dl], 1);
        if (pos < CAP) {
            int d = (b << 8) + dl;
            ssrc[((size_t)l * N_NODES + d) * CAP + pos] = (u16)(u >> 16);
        }
    }
    __syncthreads();
    int d = (b << 8) + t;
    if (d < N_NODES) cnt[l * N_NODES + d] = lcnt[t];
}

// One-shot weight prep: transpose+bf16 all weights, KV-interleaved QKV perm, bias cat,
// gbin_cnt zeroing.
__global__ void prep_kernel(const float* __restrict__ W_in,
                            const float* __restrict__ Wq, const float* __restrict__ Wk,
                            const float* __restrict__ Wv, const float* __restrict__ Wo,
                            const float* __restrict__ Wf1, const float* __restrict__ Wf2,
                            const float* __restrict__ bq, const float* __restrict__ bk,
                            const float* __restrict__ bv,
                            bf16* __restrict__ win_t, bf16* __restrict__ wqkv_t,
                            bf16* __restrict__ wo_t, bf16* __restrict__ wf1_t,
                            bf16* __restrict__ wf2_t, float* __restrict__ bqkv,
                            int* __restrict__ gbin_cnt)
{
    int id = blockIdx.x * blockDim.x + threadIdx.x;
    if (id < 16384) {
        int n = id >> 7, k = id & 127;
        win_t[id] = __float2bfloat16(W_in[k * 128 + n]);
        return;
    }
    id -= 16384;
    if (id < NLAYER * 49152) {           // QKV, rows permuted for kv-interleave
        int l = id / 49152, j = id % 49152;
        int r = j >> 7, k = j & 127;
        const float* Ws; int col;
        if (r < 128) { Ws = Wq; col = r; }
        else {
            int u = r - 128, hh = u >> 5, w = u & 31;
            if (w < 16) { Ws = Wk; col = hh * 16 + w; }
            else        { Ws = Wv; col = hh * 16 + w - 16; }
        }
        wqkv_t[(size_t)l * 49152 + j] = __float2bfloat16(Ws[(size_t)l * 16384 + k * 128 + col]);
        return;
    }
    id -= NLAYER * 49152;
    if (id < NLAYER * 16384) {
        int l = id / 16384, j = id % 16384;
        int n = j >> 7, k = j & 127;
        wo_t[id] = __float2bfloat16(Wo[(size_t)l * 16384 + k * 128 + n]);
        return;
    }
    id -= NLAYER * 16384;
    if (id < NLAYER * 32768) {           // wf1: [256][128] from [128][256]
        int l = id / 32768, j = id % 32768;
        int n = j >> 7, k = j & 127;
        wf1_t[id] = __float2bfloat16(Wf1[(size_t)l * 32768 + k * 256 + n]);
        return;
    }
    id -= NLAYER * 32768;
    if (id < NLAYER * 32768) {           // wf2: [128][256] from [256][128]
        int l = id / 32768, j = id % 32768;
        int n = j >> 8, k = j & 255;
        wf2_t[id] = __float2bfloat16(Wf2[(size_t)l * 32768 + k * 128 + n]);
        return;
    }
    id -= NLAYER * 32768;
    if (id < NLAYER * 384) {             // bias cat with same perm
        int l = id / 384, r = id % 384;
        float v;
        if (r < 128) v = bq[l * 128 + r];
        else {
            int u = r - 128, hh = u >> 5, w = u & 31;
            v = (w < 16) ? bk[l * 128 + hh * 16 + w] : bv[l * 128 + hh * 16 + w - 16];
        }
        bqkv[l * 384 + r] = v;
        return;
    }
    id -= NLAYER * 384;
    if (id < 2 * NBIN) gbin_cnt[id] = 0;
}

// Input GEMM with in-flight f32->bf16 conversion of A:
// h = x @ W_in + b_in (f32 out + bf16 shadow). Same LDS layout / K-chunk order /
// rounding point as xb_kernel+gemm_mfma -> bit-identical.
__global__ __launch_bounds__(256) void gemm_in(
    const float* __restrict__ x, const bf16* __restrict__ Wt,
    const float* __restrict__ bias,
    float* __restrict__ Cf, bf16* __restrict__ Cb)
{
    __shared__ float4 As4[1024];
    __shared__ float4 Bs4[1024];
    char* As = (char*)As4;
    char* Bs = (char*)Bs4;
    const int t = threadIdx.x;
    const int wave = t >> 6, lane = t & 63;
    const int wr = wave >> 1, wc = wave & 1;
    const int r0 = blockIdx.x * 128, c0 = blockIdx.y * 128;

    f32x4 acc[4][4] = {};

    const int lrow   = t >> 3;
    const int lcol16 = (t & 7) * 16;   // byte col in 128B row (8 bf16 = 8 f32 src)

    for (int k0 = 0; k0 < 128; k0 += 64) {
        #pragma unroll
        for (int p = 0; p < 4; p++) {
            int row = p * 32 + lrow;
            int grow = r0 + row;
            // load 8 f32, convert to 8 bf16 (16B)
            float4 a0 = make_float4(0.f, 0.f, 0.f, 0.f), a1 = a0;
            if (grow < N_NODES) {
                const float* ap = x + (size_t)grow * 128 + k0 + (t & 7) * 8;
                a0 = *(const float4*)(ap);
                a1 = *(const float4*)(ap + 4);
            }
            u32 w0 = ((u32)bfbits(a0.y) << 16) | bfbits(a0.x);
            u32 w1 = ((u32)bfbits(a0.w) << 16) | bfbits(a0.z);
            u32 w2 = ((u32)bfbits(a1.y) << 16) | bfbits(a1.x);
            u32 w3 = ((u32)bfbits(a1.w) << 16) | bfbits(a1.z);
            float4 bv = *(const float4*)((const char*)(Wt + (size_t)(c0 + row) * 128 + k0) + lcol16);
            int sw = lcol16 ^ ((row & 7) << 4);
            *(uint4*)(As + row * 128 + sw) = make_uint4(w0, w1, w2, w3);
            *(float4*)(Bs + row * 128 + sw) = bv;
        }
        __syncthreads();
        #pragma unroll
        for (int kk = 0; kk < 2; kk++) {
            bf16x8 af[4], bfr[4];
            int kbyte = kk * 64 + (lane >> 4) * 16;
            #pragma unroll
            for (int m = 0; m < 4; m++) {
                int rowa = wr * 64 + m * 16 + (lane & 15);
                af[m]  = *(const bf16x8*)(As + rowa * 128 + (kbyte ^ ((rowa & 7) << 4)));
                int rowb = wc * 64 + m * 16 + (lane & 15);
                bfr[m] = *(const bf16x8*)(Bs + rowb * 128 + (kbyte ^ ((rowb & 7) << 4)));
            }
            #pragma unroll
            for (int m = 0; m < 4; m++)
                #pragma unroll
                for (int n = 0; n < 4; n++)
                    acc[m][n] = __builtin_amdgcn_mfma_f32_16x16x32_bf16(af[m], bfr[n], acc[m][n], 0, 0, 0);
        }
        __syncthreads();
    }

    const int colbase = c0 + wc * 64 + (lane & 15);
    const int rowbase = r0 + wr * 64 + ((lane >> 4) << 2);
    #pragma unroll
    for (int n = 0; n < 4; n++) {
        int col = colbase + n * 16;
        float bsv = bias[col];
        #pragma unroll
        for (int m = 0; m < 4; m++) {
            #pragma unroll
            for (int i = 0; i < 4; i++) {
                int row = rowbase + m * 16 + i;
                if (row < N_NODES) {
                    float v = acc[m][n][i] + bsv;
                    Cf[(size_t)row * 128 + col] = v;
                    Cb[(size_t)row * 128 + col] = __float2bfloat16(v);
                }
            }
        }
    }
}

// C[M,Nc] = A[M,K] @ W + bias; A bf16 [*,lda], Wt bf16 [Nc,K] transposed.
__global__ __launch_bounds__(256) void gemm_mfma(
    const bf16* __restrict__ A, const bf16* __restrict__ Wt,
    const float* __restrict__ bias,
    float* __restrict__ Cf, bf16* __restrict__ Cb,
    int Mvalid, int K, int Nc, int lda, int relu)
{
    __shared__ float4 As4[1024];
    __shared__ float4 Bs4[1024];
    char* As = (char*)As4;
    char* Bs = (char*)Bs4;
    const int t = threadIdx.x;
    const int wave = t >> 6, lane = t & 63;
    const int wr = wave >> 1, wc = wave & 1;
    const int r0 = blockIdx.x * 128, c0 = blockIdx.y * 128;

    f32x4 acc[4][4] = {};

    const int lrow   = t >> 3;
    const int lcol16 = (t & 7) * 16;

    for (int k0 = 0; k0 < K; k0 += 64) {
        #pragma unroll
        for (int p = 0; p < 4; p++) {
            int row = p * 32 + lrow;
            float4 av = *(const float4*)((const char*)(A  + (size_t)(r0 + row) * lda + k0) + lcol16);
            float4 bv = *(const float4*)((const char*)(Wt + (size_t)(c0 + row) * K + k0) + lcol16);
            int sw = lcol16 ^ ((row & 7) << 4);
            *(float4*)(As + row * 128 + sw) = av;
            *(float4*)(Bs + row * 128 + sw) = bv;
        }
        __syncthreads();
        #pragma unroll
        for (int kk = 0; kk < 2; kk++) {
            bf16x8 af[4], bfr[4];
            int kbyte = kk * 64 + (lane >> 4) * 16;
            #pragma unroll
            for (int m = 0; m < 4; m++) {
                int rowa = wr * 64 + m * 16 + (lane & 15);
                af[m]  = *(const bf16x8*)(As + rowa * 128 + (kbyte ^ ((rowa & 7) << 4)));
                int rowb = wc * 64 + m * 16 + (lane & 15);
                bfr[m] = *(const bf16x8*)(Bs + rowb * 128 + (kbyte ^ ((rowb & 7) << 4)));
            }
            #pragma unroll
            for (int m = 0; m < 4; m++)
                #pragma unroll
                for (int n = 0; n < 4; n++)
                    acc[m][n] = __builtin_amdgcn_mfma_f32_16x16x32_bf16(af[m], bfr[n], acc[m][n], 0, 0, 0);
        }
        __syncthreads();
    }

    const int colbase = c0 + wc * 64 + (lane & 15);
    const int rowbase = r0 + wr * 64 + ((lane >> 4) << 2);
    #pragma unroll
    for (int n = 0; n < 4; n++) {
        int col = colbase + n * 16;
        float bsv = bias[col];
        #pragma unroll
        for (int m = 0; m < 4; m++) {
            #pragma unroll
            for (int i = 0; i < 4; i++) {
                int row = rowbase + m * 16 + i;
                if (row < Mvalid) {
                    float v = acc[m][n][i] + bsv;
                    if (relu) v = fmaxf(v, 0.f);
                    if (Cf) Cf[(size_t)row * Nc + col] = v;
                    if (Cb) Cb[(size_t)row * Nc + col] = __float2bfloat16(v);
                }
            }
        }
    }
}

// Fused layer tail: h = LN2( LN1(h + agg@Wo + bo) + FFN(LN1(...)) ). 48KB LDS.
__global__ __launch_bounds__(256) void tail_fused(
    const bf16* __restrict__ qkv,    // agg in q-section, lda=384
    const bf16* __restrict__ wo_t,   // [128][128]
    const float* __restrict__ bo,
    const float* __restrict__ g1, const float* __restrict__ be1,
    const bf16* __restrict__ Wf1t,   // [256][128]
    const float* __restrict__ b1,
    const bf16* __restrict__ Wf2t,   // [128][256]
    const float* __restrict__ b2,
    const float* __restrict__ g2, const float* __restrict__ be2,
    float* __restrict__ h, bf16* __restrict__ hb)
{
    __shared__ char lds[49152];
    char* AsA = lds;                 // part1: 64 x 128B A-chunk (overlaps Ah1)
    char* Ah1 = lds;                 // 64 x 256B h1 (bf16, swizzled)
    char* Xs  = lds + 16384;         // 64 x 256B X-half (bf16, swizzled)
    char* Bs  = lds + 32768;         // 16KB weight chunk buffer
    const int t = threadIdx.x;
    const int w = t >> 6, lane = t & 63;
    const int r0 = blockIdx.x * 64;
    const int c = lane & 15, sub = lane >> 4;

    // ---- part 1: T = agg @ Wo (K=128 in 2 chunks of 64) ----
    f32x4 acc0[8] = {};
    #pragma unroll
    for (int k0 = 0; k0 < 128; k0 += 64) {
        {
            int row = t >> 2;
            int c16 = (t & 3) * 32;
            const char* ap = (const char*)(qkv + (size_t)(r0 + row) * 384 + k0);
            float4 a0 = *(const float4*)(ap + c16);
            float4 a1 = *(const float4*)(ap + c16 + 16);
            *(float4*)(AsA + row * 128 + ((c16)      ^ ((row & 7) << 4))) = a0;
            *(float4*)(AsA + row * 128 + ((c16 + 16) ^ ((row & 7) << 4))) = a1;
        }
        {
            int row = t >> 1;
            int c16 = (t & 1) * 64;
            const char* bp = (const char*)(wo_t + (size_t)row * 128 + k0);
            #pragma unroll
            for (int j = 0; j < 4; j++) {
                float4 b = *(const float4*)(bp + c16 + j * 16);
                *(float4*)(Bs + row * 128 + ((c16 + j * 16) ^ ((row & 7) << 4))) = b;
            }
        }
        __syncthreads();
        #pragma unroll
        for (int kk = 0; kk < 2; kk++) {
            int kbyte = kk * 64 + sub * 16;
            int rowa = w * 16 + c;
            bf16x8 af = *(const bf16x8*)(AsA + rowa * 128 + (kbyte ^ ((rowa & 7) << 4)));
            #pragma unroll
            for (int n = 0; n < 8; n++) {
                int rowb = n * 16 + c;
                bf16x8 bf8 = *(const bf16x8*)(Bs + rowb * 128 + (kbyte ^ ((rowb & 7) << 4)));
                acc0[n] = __builtin_amdgcn_mfma_f32_16x16x32_bf16(af, bf8, acc0[n], 0, 0, 0);
            }
        }
        __syncthreads();
    }

    // ---- LN1: h1 in regs + Ah1 in LDS (bf16) ----
    float h1v[8][4];
    {
        float bsv[8], gv[8], bev[8];
        #pragma unroll
        for (int n = 0; n < 8; n++) {
            int col = n * 16 + c;
            bsv[n] = bo[col]; gv[n] = g1[col]; bev[n] = be1[col];
        }
        #pragma unroll
        for (int i = 0; i < 4; i++) {
            int row = r0 + w * 16 + sub * 4 + i;
            bool ok = row < N_NODES;
            float x[8];
            float s = 0.f;
            #pragma unroll
            for (int n = 0; n < 8; n++) {
                float res = ok ? h[(size_t)row * D + n * 16 + c] : 0.f;
                x[n] = res + acc0[n][i] + bsv[n];
                s += x[n];
            }
            s += __shfl_xor(s, 1); s += __shfl_xor(s, 2);
            s += __shfl_xor(s, 4); s += __shfl_xor(s, 8);
            float mean = s * (1.f / 128.f);
            float v = 0.f;
            #pragma unroll
            for (int n = 0; n < 8; n++) { float dd = x[n] - mean; v += dd * dd; }
            v += __shfl_xor(v, 1); v += __shfl_xor(v, 2);
            v += __shfl_xor(v, 4); v += __shfl_xor(v, 8);
            float rstd = rsqrtf(v * (1.f / 128.f) + 1e-5f);
            int lrow = w * 16 + sub * 4 + i;
            #pragma unroll
            for (int n = 0; n < 8; n++) {
                float o = (x[n] - mean) * rstd * gv[n] + bev[n];
                h1v[n][i] = o;
                int byte = (n * 16 + c) * 2;
                int addr = lrow * 256 + ((byte & ~15) ^ ((lrow & 7) << 4)) + (byte & 15);
                *(u16*)(Ah1 + addr) = bfbits(o);
            }
        }
    }
    __syncthreads();

    // ---- parts 2+3 interleaved per 128-hidden half ----
    f32x4 acc2[8] = {};
    #pragma unroll
    for (int xh = 0; xh < 2; xh++) {
        f32x4 acc1[8] = {};
        #pragma unroll
        for (int kc = 0; kc < 2; kc++) {
            {
                int row = t >> 1;
                int off = (t & 1) * 64;
                const char* bp = (const char*)Wf1t + (size_t)(xh * 128 + row) * 256 + kc * 128 + off;
                #pragma unroll
                for (int j = 0; j < 4; j++) {
                    float4 v = *(const float4*)(bp + j * 16);
                    *(float4*)(Bs + row * 128 + ((off + j * 16) ^ ((row & 7) << 4))) = v;
                }
            }
            __syncthreads();
            #pragma unroll
            for (int kkl = 0; kkl < 2; kkl++) {
                int abyte = (kc * 2 + kkl) * 64 + sub * 16;
                int rowa = w * 16 + c;
                bf16x8 af = *(const bf16x8*)(Ah1 + rowa * 256 + (abyte ^ ((rowa & 7) << 4)));
                int bbyte = kkl * 64 + sub * 16;
                #pragma unroll
                for (int n = 0; n < 8; n++) {
                    int rowb = n * 16 + c;
                    bf16x8 bf8 = *(const bf16x8*)(Bs + rowb * 128 + (bbyte ^ ((rowb & 7) << 4)));
                    acc1[n] = __builtin_amdgcn_mfma_f32_16x16x32_bf16(af, bf8, acc1[n], 0, 0, 0);
                }
            }
            __syncthreads();
        }
        #pragma unroll
        for (int n = 0; n < 8; n++) {
            float bs = b1[xh * 128 + n * 16 + c];
            #pragma unroll
            for (int i = 0; i < 4; i++) {
                int row = w * 16 + sub * 4 + i;
                float v = fmaxf(acc1[n][i] + bs, 0.f);
                int byte = (n * 16 + c) * 2;
                int addr = row * 256 + ((byte & ~15) ^ ((row & 7) << 4)) + (byte & 15);
                *(u16*)(Xs + addr) = bfbits(v);
            }
        }
        __syncthreads();
        #pragma unroll
        for (int oh = 0; oh < 2; oh++) {
            {
                int row = t >> 2;
                int off = (t & 3) * 64;
                const char* bp = (const char*)Wf2t + (size_t)(oh * 64 + row) * 512 + xh * 256 + off;
                #pragma unroll
                for (int j = 0; j < 4; j++) {
                    float4 v = *(const float4*)(bp + j * 16);
                    *(float4*)(Bs + row * 256 + ((off + j * 16) ^ ((row & 7) << 4))) = v;
                }
            }
            __syncthreads();
            #pragma unroll
            for (int kkl = 0; kkl < 4; kkl++) {
                int xbyte = kkl * 64 + sub * 16;
                int rowa = w * 16 + c;
                bf16x8 af = *(const bf16x8*)(Xs + rowa * 256 + (xbyte ^ ((rowa & 7) << 4)));
                #pragma unroll
                for (int n = 0; n < 4; n++) {
                    int rowb = n * 16 + c;
                    bf16x8 bf8 = *(const bf16x8*)(Bs + rowb * 256 + (xbyte ^ ((rowb & 7) << 4)));
                    acc2[oh * 4 + n] = __builtin_amdgcn_mfma_f32_16x16x32_bf16(af, bf8, acc2[oh * 4 + n], 0, 0, 0);
                }
            }
            __syncthreads();
        }
    }

    // ---- LN2 epilogue ----
    {
        float bsv[8], gv[8], bev[8];
        #pragma unroll
        for (int n = 0; n < 8; n++) {
            int col = n * 16 + c;
            bsv[n] = b2[col]; gv[n] = g2[col]; bev[n] = be2[col];
        }
        #pragma unroll
        for (int i = 0; i < 4; i++) {
            int row = r0 + w * 16 + sub * 4 + i;
            bool ok = row < N_NODES;
            float x[8];
            float s = 0.f;
            #pragma unroll
            for (int n = 0; n < 8; n++) {
                x[n] = h1v[n][i] + acc2[n][i] + bsv[n];
                s += x[n];
            }
            s += __shfl_xor(s, 1); s += __shfl_xor(s, 2);
            s += __shfl_xor(s, 4); s += __shfl_xor(s, 8);
            float mean = s * (1.f / 128.f);
            float v = 0.f;
            #pragma unroll
            for (int n = 0; n < 8; n++) { float dd = x[n] - mean; v += dd * dd; }
            v += __shfl_xor(v, 1); v += __shfl_xor(v, 2);
            v += __shfl_xor(v, 4); v += __shfl_xor(v, 8);
            float rstd = rsqrtf(v * (1.f / 128.f) + 1e-5f);
            if (ok) {
                #pragma unroll
                for (int n = 0; n < 8; n++) {
                    float o = (x[n] - mean) * rstd * gv[n] + bev[n];
                    h [(size_t)row * D + n * 16 + c] = o;
                    hb[(size_t)row * D + n * 16 + c] = __float2bfloat16(o);
                }
            }
        }
    }
}

// Fused single-pass attention on qkv[M][384] with KV-interleaved layout.
__global__ __launch_bounds__(256) void attn_fused(
    const bf16* __restrict__ qkv,
    const int* __restrict__ cnt, const u16* __restrict__ ssrc,
    bf16* __restrict__ aggout)
{
    const float S2 = 0.25f * 1.44269504088896f;   // scale/ln2
    int wid = threadIdx.x >> 6, lane = threadIdx.x & 63;
    int d = blockIdx.x * 4 + wid;
    if (d >= N_NODES) return;
    int slot = lane >> 3, h = lane & 7;

    const u32* qr = (const u32*)(qkv + (size_t)d * 384 + h * DH);
    float qf[16];
    {
        uint4 q0 = *(const uint4*)(qr);
        uint4 q1 = *(const uint4*)(qr + 4);
        qf[0]=bflo(q0.x); qf[1]=bfhi(q0.x); qf[2]=bflo(q0.y); qf[3]=bfhi(q0.y);
        qf[4]=bflo(q0.z); qf[5]=bfhi(q0.z); qf[6]=bflo(q0.w); qf[7]=bfhi(q0.w);
        qf[8]=bflo(q1.x); qf[9]=bfhi(q1.x); qf[10]=bflo(q1.y); qf[11]=bfhi(q1.y);
        qf[12]=bflo(q1.z); qf[13]=bfhi(q1.z); qf[14]=bflo(q1.w); qf[15]=bfhi(q1.w);
    }

    int deg = cnt[d];
    if (deg > CAP) deg = CAP;
    const u16* bp = ssrc + (size_t)d * CAP;
    float m2 = -INFINITY, den = 0.f;
    float acc[16] = {};

    for (int i = slot; i < deg; i += 8) {
        int s = bp[i];
        const uint4* kvp = (const uint4*)(qkv + (size_t)s * 384 + 128 + h * 32);
        uint4 k0 = kvp[0], k1 = kvp[1], v0 = kvp[2], v1 = kvp[3];
        float p = qf[0]*bflo(k0.x) + qf[1]*bfhi(k0.x)
                + qf[2]*bflo(k0.y) + qf[3]*bfhi(k0.y)
                + qf[4]*bflo(k0.z) + qf[5]*bfhi(k0.z)
                + qf[6]*bflo(k0.w) + qf[7]*bfhi(k0.w)
                + qf[8]*bflo(k1.x) + qf[9]*bfhi(k1.x)
                + qf[10]*bflo(k1.y) + qf[11]*bfhi(k1.y)
                + qf[12]*bflo(k1.z) + qf[13]*bfhi(k1.z)
                + qf[14]*bflo(k1.w) + qf[15]*bfhi(k1.w);
        float p2 = p * S2;
        float w;
        if (p2 > m2 + 8.f) {
            float f = exp2f(m2 - p2);
            den *= f;
            #pragma unroll
            for (int j = 0; j < 16; j++) acc[j] *= f;
            m2 = p2;
            w = 1.f;
        } else {
            w = exp2f(p2 - m2);
        }
        den += w;
        acc[0]  += w*bflo(v0.x); acc[1]  += w*bfhi(v0.x);
        acc[2]  += w*bflo(v0.y); acc[3]  += w*bfhi(v0.y);
        acc[4]  += w*bflo(v0.z); acc[5]  += w*bfhi(v0.z);
        acc[6]  += w*bflo(v0.w); acc[7]  += w*bfhi(v0.w);
        acc[8]  += w*bflo(v1.x); acc[9]  += w*bfhi(v1.x);
        acc[10] += w*bflo(v1.y); acc[11] += w*bfhi(v1.y);
        acc[12] += w*bflo(v1.z); acc[13] += w*bfhi(v1.z);
        acc[14] += w*bflo(v1.w); acc[15] += w*bfhi(v1.w);
    }

    #pragma unroll
    for (int o = 8; o < 64; o <<= 1) {
        float om   = __shfl_xor(m2, o);
        float oden = __shfl_xor(den, o);
        float M = fmaxf(m2, om);
        float fa = (m2 > -INFINITY) ? exp2f(m2 - M) : 0.f;
        float fb = (om > -INFINITY) ? exp2f(om - M) : 0.f;
        den = den * fa + oden * fb;
        #pragma unroll
        for (int j = 0; j < 16; j++) {
            float oa = __shfl_xor(acc[j], o);
            acc[j] = acc[j] * fa + oa * fb;
        }
        m2 = M;
    }

    float r = 1.f / (den + 1e-9f);
    float o0 = 0.f, o1 = 0.f;
    #pragma unroll
    for (int j = 0; j < 8; j++) {
        if (slot == j) { o0 = acc[2 * j]; o1 = acc[2 * j + 1]; }
    }
    bf16* op = aggout + (size_t)d * 384 + h * DH + slot * 2;
    op[0] = __float2bfloat16(o0 * r);
    op[1] = __float2bfloat16(o1 * r);
}

// merged pos+neg predictor
__global__ void predict_kernel(const float* __restrict__ h,
                               const int* __restrict__ ps, const int* __restrict__ pd,
                               const int* __restrict__ ns, const int* __restrict__ nd,
                               const float* __restrict__ Wp1, const float* __restrict__ bp1,
                               const float* __restrict__ Wp2, const float* __restrict__ bp2,
                               float* __restrict__ out)
{
    __shared__ float z[128];
    int p = blockIdx.x;
    int a, b;
    if (p < PP) { a = ps[p]; b = pd[p]; }
    else        { a = ns[p - PP]; b = nd[p - PP]; }
    int t = threadIdx.x;
    z[t]      = h[(size_t)a * D + t]      * h[(size_t)b * D + t];
    z[t + 64] = h[(size_t)a * D + t + 64] * h[(size_t)b * D + t + 64];
    __syncthreads();
    float acc = bp1[t];
    #pragma unroll 4
    for (int i = 0; i < 128; i++) acc += z[i] * Wp1[(size_t)i * 64 + t];
    acc = acc > 0.f ? acc : 0.2f * acc;
    float part = acc * Wp2[t];
    #pragma unroll
    for (int o = 32; o > 0; o >>= 1) part += __shfl_down(part, o);
    if (t == 0) out[p] = part + bp2[0];
}

extern "C" void kernel_launch(void* const* d_in, const int* in_sizes, int n_in,
                              void* d_out, int out_size, void* d_ws, size_t ws_size,
                              hipStream_t stream)
{
    const float* x       = (const float*)d_in[0];
    const int*   src     = (const int*)d_in[1];
    const int*   dst     = (const int*)d_in[2];
    const int*   pos_src = (const int*)d_in[3];
    const int*   pos_dst = (const int*)d_in[4];
    const int*   neg_src = (const int*)d_in[5];
    const int*   neg_dst = (const int*)d_in[6];
    const float* W_in = (const float*)d_in[7];
    const float* b_in = (const float*)d_in[8];
    const float* Wq = (const float*)d_in[9];
    const float* bq = (const float*)d_in[10];
    const float* Wk = (const float*)d_in[11];
    const float* bk = (const float*)d_in[12];
    const float* Wv = (const float*)d_in[13];
    const float* bv = (const float*)d_in[14];
    const float* Wo = (const float*)d_in[15];
    const float* bo = (const float*)d_in[16];
    const float* ln1g = (const float*)d_in[17];
    const float* ln1b = (const float*)d_in[18];
    const float* Wf1 = (const float*)d_in[19];
    const float* bf1 = (const float*)d_in[20];
    const float* Wf2 = (const float*)d_in[21];
    const float* bf2 = (const float*)d_in[22];
    const float* ln2g = (const float*)d_in[23];
    const float* ln2b = (const float*)d_in[24];
    const float* Wp1 = (const float*)d_in[25];
    const float* bp1 = (const float*)d_in[26];
    const float* Wp2 = (const float*)d_in[27];
    const float* bp2 = (const float*)d_in[28];

    float* out = (float*)d_out;
    float* h   = out + 2 * PP;                      // [N,D] f32 residual stream

    // workspace layout
    bf16* B    = (bf16*)d_ws;
    bf16* qkvb = B;                                 // [MPAD][384]
    bf16* hb   = B + (size_t)MPAD * 384;            // [MPAD][128]
    int*  cnt  = (int*)(hb + (size_t)MPAD * 128);   // [2][N]
    u16*  ssrc = (u16*)(cnt + 2 * N_NODES);         // [2][N*CAP]
    bf16* wtb  = (bf16*)(ssrc + (size_t)2 * N_NODES * CAP);
    bf16* win_t  = wtb;                             // 16384
    bf16* wqkv_t = wtb + 16384;                     // 2*49152 (kv-interleave perm)
    bf16* wo_t   = wtb + 16384 + 98304;             // 2*16384
    bf16* wf1_t  = wtb + 16384 + 98304 + 32768;     // 2*32768
    bf16* wf2_t  = wtb + 16384 + 98304 + 32768 + 65536; // 2*32768
    float* bqkv  = (float*)(wtb + 16384 + 98304 + 32768 + 65536 + 65536); // [L][384]
    int*  gbin_cnt = (int*)(bqkv + NLAYER * 384);   // [2][NBIN]
    u32*  gbin     = (u32*)(gbin_cnt + 2 * NBIN);   // [2][NBIN][GCAP]

    auto cdiv = [](int a, int b) { return (a + b - 1) / b; };
    const int GX = MPAD / 128;                      // 391
    const int GL = MPAD / 64;                       // 782

    // weight prep (+ gbin_cnt zero), CSR build
    prep_kernel<<<1093, 256, 0, stream>>>(W_in, Wq, Wk, Wv, Wo, Wf1, Wf2, bq, bk, bv,
                                          win_t, wqkv_t, wo_t, wf1_t, wf2_t, bqkv, gbin_cnt);
    bin_kernel<<<dim3(cdiv(NE, CHUNK), 2), 256, 0, stream>>>(dst, src, gbin, gbin_cnt);
    expand_kernel<<<dim3(NBIN, 2), 256, 0, stream>>>(gbin, gbin_cnt, cnt, ssrc);

    // h = x @ W_in + b_in  (f32->bf16 conversion fused into stager)
    gemm_in<<<dim3(GX, 1), 256, 0, stream>>>(x, win_t, b_in, h, hb);

    for (int l = 0; l < NLAYER; l++) {
        gemm_mfma<<<dim3(GX, 3), 256, 0, stream>>>(hb, wqkv_t + l * 49152, bqkv + l * 384,
                                                   nullptr, qkvb, N_NODES, 128, 384, 128, 0);

        attn_fused<<<cdiv(N_NODES, 4), 256, 0, stream>>>(qkvb, cnt + l * N_NODES,
                                                         ssrc + (size_t)l * N_NODES * CAP, qkvb);

        tail_fused<<<GL, 256, 0, stream>>>(qkvb, wo_t + l * 16384, bo + l * D,
                                           ln1g + l * D, ln1b + l * D,
                                           wf1_t + l * 32768, bf1 + l * FF,
                                           wf2_t + l * 32768, bf2 + l * D,
                                           ln2g + l * D, ln2b + l * D, h, hb);
    }

    predict_kernel<<<2 * PP, 64, 0, stream>>>(h, pos_src, pos_dst, neg_src, neg_dst,
                                              Wp1, bp1, Wp2, bp2, out);
}

// Round 19
// 336.232 us; speedup vs baseline: 1.2102x; 1.0122x over previous
//
#include <hip/hip_runtime.h>
#include <hip/hip_bf16.h>
#include <math.h>

#define N_NODES 50000
#define NE      800000
#define D       128
#define H       8
#define DH      16
#define NLAYER  2
#define IN_F    128
#define PP      8192
#define FF      256
#define MPAD    50048   // 391 * 128 = 782 * 64
#define CAP     96      // bucket capacity (mean deg 16; P(>=96)~1e-40)
#define NBIN    196     // bins of 256 nodes: bin = d >> 8
#define BCAP    48      // per-chunk per-bin LDS cap
#define GCAP    4608    // per-bin global cap
#define CHUNK   2048    // edges per phase-1 block

typedef short  bf16x8 __attribute__((ext_vector_type(8)));
typedef float  f32x4  __attribute__((ext_vector_type(4)));
typedef __hip_bfloat16 bf16;
typedef unsigned short u16;
typedef unsigned int   u32;

__device__ __forceinline__ float bflo(u32 u) { return __uint_as_float(u << 16); }
__device__ __forceinline__ float bfhi(u32 u) { return __uint_as_float(u & 0xffff0000u); }
__device__ __forceinline__ u16 bfbits(float f) { bf16 t = __float2bfloat16(f); return *(u16*)&t; }

// Phase 1: bin edges by dst>>8 via LDS, flush dense appends to per-bin global arrays.
__global__ __launch_bounds__(256) void bin_kernel(
    const int* __restrict__ dst, const int* __restrict__ src,
    u32* __restrict__ gbin, int* __restrict__ gbin_cnt)
{
    __shared__ u32 ent[NBIN * BCAP];
    __shared__ int bcnt[NBIN];
    const int t = threadIdx.x, l = blockIdx.y;
    const int base = blockIdx.x * CHUNK;
    if (t < NBIN) bcnt[t] = 0;
    __syncthreads();
    #pragma unroll
    for (int j = 0; j < CHUNK / 256; j++) {
        int e = base + j * 256 + t;
        if (e < NE) {
            int d = dst[(size_t)l * NE + e];
            int s = src[(size_t)l * NE + e];
            int bin = d >> 8;
            int slot = atomicAdd(&bcnt[bin], 1);
            if (slot < BCAP) ent[bin * BCAP + slot] = ((u32)s << 16) | (u32)(d & 255);
        }
    }
    __syncthreads();
    if (t < NBIN) {
        int c = bcnt[t]; if (c > BCAP) c = BCAP;
        if (c > 0) {
            int gb = atomicAdd(&gbin_cnt[l * NBIN + t], c);
            u32* gp = gbin + ((size_t)l * NBIN + t) * GCAP;
            for (int i = 0; i < c; i++)
                if (gb + i < GCAP) gp[gb + i] = ent[t * BCAP + i];
        }
    }
}

// Phase 2: per (bin, layer) block expands packed edges into CAP-buckets via LDS counters.
__global__ __launch_bounds__(256) void expand_kernel(
    const u32* __restrict__ gbin, const int* __restrict__ gbin_cnt,
    int* __restrict__ cnt, u16* __restrict__ ssrc)
{
    __shared__ int lcnt[256];
    const int t = threadIdx.x, b = blockIdx.x, l = blockIdx.y;
    lcnt[t] = 0;
    __syncthreads();
    int n = gbin_cnt[l * NBIN + b]; if (n > GCAP) n = GCAP;
    const u32* gp = gbin + ((size_t)l * NBIN + b) * GCAP;
    for (int i = t; i < n; i += 256) {
        u32 u = gp[i];
        int dl = (int)(u & 255);
        int pos = atomicAdd(&lcnt[dl], 1);
        if (pos < CAP) {
            int d = (b << 8) + dl;
            ssrc[((size_t)l * N_NODES + d) * CAP + pos] = (u16)(u >> 16);
        }
    }
    __syncthreads();
    int d = (b << 8) + t;
    if (d < N_NODES) cnt[l * N_NODES + d] = lcnt[t];
}

// One-shot weight prep: transpose+bf16 all weights, KV-interleaved QKV perm, bias cat,
// gbin_cnt zeroing.
__global__ void prep_kernel(const float* __restrict__ W_in,
                            const float* __restrict__ Wq, const float* __restrict__ Wk,
                            const float* __restrict__ Wv, const float* __restrict__ Wo,
                            const float* __restrict__ Wf1, const float* __restrict__ Wf2,
                            const float* __restrict__ bq, const float* __restrict__ bk,
                            const float* __restrict__ bv,
                            bf16* __restrict__ win_t, bf16* __restrict__ wqkv_t,
                            bf16* __restrict__ wo_t, bf16* __restrict__ wf1_t,
                            bf16* __restrict__ wf2_t, float* __restrict__ bqkv,
                            int* __restrict__ gbin_cnt)
{
    int id = blockIdx.x * blockDim.x + threadIdx.x;
    if (id < 16384) {
        int n = id >> 7, k = id & 127;
        win_t[id] = __float2bfloat16(W_in[k * 128 + n]);
        return;
    }
    id -= 16384;
    if (id < NLAYER * 49152) {           // QKV, rows permuted for kv-interleave
        int l = id / 49152, j = id % 49152;
        int r = j >> 7, k = j & 127;
        const float* Ws; int col;
        if (r < 128) { Ws = Wq; col = r; }
        else {
            int u = r - 128, hh = u >> 5, w = u & 31;
            if (w < 16) { Ws = Wk; col = hh * 16 + w; }
            else        { Ws = Wv; col = hh * 16 + w - 16; }
        }
        wqkv_t[(size_t)l * 49152 + j] = __float2bfloat16(Ws[(size_t)l * 16384 + k * 128 + col]);
        return;
    }
    id -= NLAYER * 49152;
    if (id < NLAYER * 16384) {
        int l = id / 16384, j = id % 16384;
        int n = j >> 7, k = j & 127;
        wo_t[id] = __float2bfloat16(Wo[(size_t)l * 16384 + k * 128 + n]);
        return;
    }
    id -= NLAYER * 16384;
    if (id < NLAYER * 32768) {           // wf1: [256][128] from [128][256]
        int l = id / 32768, j = id % 32768;
        int n = j >> 7, k = j & 127;
        wf1_t[id] = __float2bfloat16(Wf1[(size_t)l * 32768 + k * 256 + n]);
        return;
    }
    id -= NLAYER * 32768;
    if (id < NLAYER * 32768) {           // wf2: [128][256] from [256][128]
        int l = id / 32768, j = id % 32768;
        int n = j >> 8, k = j & 255;
        wf2_t[id] = __float2bfloat16(Wf2[(size_t)l * 32768 + k * 128 + n]);
        return;
    }
    id -= NLAYER * 32768;
    if (id < NLAYER * 384) {             // bias cat with same perm
        int l = id / 384, r = id % 384;
        float v;
        if (r < 128) v = bq[l * 128 + r];
        else {
            int u = r - 128, hh = u >> 5, w = u & 31;
            v = (w < 16) ? bk[l * 128 + hh * 16 + w] : bv[l * 128 + hh * 16 + w - 16];
        }
        bqkv[l * 384 + r] = v;
        return;
    }
    id -= NLAYER * 384;
    if (id < 2 * NBIN) gbin_cnt[id] = 0;
}

// Input GEMM with in-flight f32->bf16 conversion of A:
// h = x @ W_in + b_in (f32 out + bf16 shadow).
__global__ __launch_bounds__(256) void gemm_in(
    const float* __restrict__ x, const bf16* __restrict__ Wt,
    const float* __restrict__ bias,
    float* __restrict__ Cf, bf16* __restrict__ Cb)
{
    __shared__ float4 As4[1024];
    __shared__ float4 Bs4[1024];
    char* As = (char*)As4;
    char* Bs = (char*)Bs4;
    const int t = threadIdx.x;
    const int wave = t >> 6, lane = t & 63;
    const int wr = wave >> 1, wc = wave & 1;
    const int r0 = blockIdx.x * 128, c0 = blockIdx.y * 128;

    f32x4 acc[4][4] = {};

    const int lrow   = t >> 3;
    const int lcol16 = (t & 7) * 16;

    for (int k0 = 0; k0 < 128; k0 += 64) {
        #pragma unroll
        for (int p = 0; p < 4; p++) {
            int row = p * 32 + lrow;
            int grow = r0 + row;
            float4 a0 = make_float4(0.f, 0.f, 0.f, 0.f), a1 = a0;
            if (grow < N_NODES) {
                const float* ap = x + (size_t)grow * 128 + k0 + (t & 7) * 8;
                a0 = *(const float4*)(ap);
                a1 = *(const float4*)(ap + 4);
            }
            u32 w0 = ((u32)bfbits(a0.y) << 16) | bfbits(a0.x);
            u32 w1 = ((u32)bfbits(a0.w) << 16) | bfbits(a0.z);
            u32 w2 = ((u32)bfbits(a1.y) << 16) | bfbits(a1.x);
            u32 w3 = ((u32)bfbits(a1.w) << 16) | bfbits(a1.z);
            float4 bv = *(const float4*)((const char*)(Wt + (size_t)(c0 + row) * 128 + k0) + lcol16);
            int sw = lcol16 ^ ((row & 7) << 4);
            *(uint4*)(As + row * 128 + sw) = make_uint4(w0, w1, w2, w3);
            *(float4*)(Bs + row * 128 + sw) = bv;
        }
        __syncthreads();
        #pragma unroll
        for (int kk = 0; kk < 2; kk++) {
            bf16x8 af[4], bfr[4];
            int kbyte = kk * 64 + (lane >> 4) * 16;
            #pragma unroll
            for (int m = 0; m < 4; m++) {
                int rowa = wr * 64 + m * 16 + (lane & 15);
                af[m]  = *(const bf16x8*)(As + rowa * 128 + (kbyte ^ ((rowa & 7) << 4)));
                int rowb = wc * 64 + m * 16 + (lane & 15);
                bfr[m] = *(const bf16x8*)(Bs + rowb * 128 + (kbyte ^ ((rowb & 7) << 4)));
            }
            #pragma unroll
            for (int m = 0; m < 4; m++)
                #pragma unroll
                for (int n = 0; n < 4; n++)
                    acc[m][n] = __builtin_amdgcn_mfma_f32_16x16x32_bf16(af[m], bfr[n], acc[m][n], 0, 0, 0);
        }
        __syncthreads();
    }

    const int colbase = c0 + wc * 64 + (lane & 15);
    const int rowbase = r0 + wr * 64 + ((lane >> 4) << 2);
    #pragma unroll
    for (int n = 0; n < 4; n++) {
        int col = colbase + n * 16;
        float bsv = bias[col];
        #pragma unroll
        for (int m = 0; m < 4; m++) {
            #pragma unroll
            for (int i = 0; i < 4; i++) {
                int row = rowbase + m * 16 + i;
                if (row < N_NODES) {
                    float v = acc[m][n][i] + bsv;
                    Cf[(size_t)row * 128 + col] = v;
                    Cb[(size_t)row * 128 + col] = __float2bfloat16(v);
                }
            }
        }
    }
}

// QKV GEMM with split outputs: cols [0,128) -> qb [M][128], cols [128,384) -> kvb [M][256].
// A = hb [M][128]; Wt = wqkv (kv-interleaved perm) [384][128].
__global__ __launch_bounds__(256) void gemm_qkv(
    const bf16* __restrict__ A, const bf16* __restrict__ Wt,
    const float* __restrict__ bias,
    bf16* __restrict__ qb, bf16* __restrict__ kvb)
{
    __shared__ float4 As4[1024];
    __shared__ float4 Bs4[1024];
    char* As = (char*)As4;
    char* Bs = (char*)Bs4;
    const int t = threadIdx.x;
    const int wave = t >> 6, lane = t & 63;
    const int wr = wave >> 1, wc = wave & 1;
    const int r0 = blockIdx.x * 128, c0 = blockIdx.y * 128;

    f32x4 acc[4][4] = {};

    const int lrow   = t >> 3;
    const int lcol16 = (t & 7) * 16;

    for (int k0 = 0; k0 < 128; k0 += 64) {
        #pragma unroll
        for (int p = 0; p < 4; p++) {
            int row = p * 32 + lrow;
            float4 av = *(const float4*)((const char*)(A  + (size_t)(r0 + row) * 128 + k0) + lcol16);
            float4 bv = *(const float4*)((const char*)(Wt + (size_t)(c0 + row) * 128 + k0) + lcol16);
            int sw = lcol16 ^ ((row & 7) << 4);
            *(float4*)(As + row * 128 + sw) = av;
            *(float4*)(Bs + row * 128 + sw) = bv;
        }
        __syncthreads();
        #pragma unroll
        for (int kk = 0; kk < 2; kk++) {
            bf16x8 af[4], bfr[4];
            int kbyte = kk * 64 + (lane >> 4) * 16;
            #pragma unroll
            for (int m = 0; m < 4; m++) {
                int rowa = wr * 64 + m * 16 + (lane & 15);
                af[m]  = *(const bf16x8*)(As + rowa * 128 + (kbyte ^ ((rowa & 7) << 4)));
                int rowb = wc * 64 + m * 16 + (lane & 15);
                bfr[m] = *(const bf16x8*)(Bs + rowb * 128 + (kbyte ^ ((rowb & 7) << 4)));
            }
            #pragma unroll
            for (int m = 0; m < 4; m++)
                #pragma unroll
                for (int n = 0; n < 4; n++)
                    acc[m][n] = __builtin_amdgcn_mfma_f32_16x16x32_bf16(af[m], bfr[n], acc[m][n], 0, 0, 0);
        }
        __syncthreads();
    }

    const int colbase = c0 + wc * 64 + (lane & 15);
    const int rowbase = r0 + wr * 64 + ((lane >> 4) << 2);
    #pragma unroll
    for (int n = 0; n < 4; n++) {
        int col = colbase + n * 16;
        float bsv = bias[col];
        #pragma unroll
        for (int m = 0; m < 4; m++) {
            #pragma unroll
            for (int i = 0; i < 4; i++) {
                int row = rowbase + m * 16 + i;
                if (row < N_NODES) {
                    float v = acc[m][n][i] + bsv;
                    if (col < 128) qb [(size_t)row * 128 + col]         = __float2bfloat16(v);
                    else           kvb[(size_t)row * 256 + (col - 128)] = __float2bfloat16(v);
                }
            }
        }
    }
}

// Fused layer tail: h = LN2( LN1(h + agg@Wo + bo) + FFN(LN1(...)) ). 48KB LDS.
__global__ __launch_bounds__(256) void tail_fused(
    const bf16* __restrict__ qb,     // agg [M][128]
    const bf16* __restrict__ wo_t,   // [128][128]
    const float* __restrict__ bo,
    const float* __restrict__ g1, const float* __restrict__ be1,
    const bf16* __restrict__ Wf1t,   // [256][128]
    const float* __restrict__ b1,
    const bf16* __restrict__ Wf2t,   // [128][256]
    const float* __restrict__ b2,
    const float* __restrict__ g2, const float* __restrict__ be2,
    float* __restrict__ h, bf16* __restrict__ hb)
{
    __shared__ char lds[49152];
    char* AsA = lds;                 // part1: 64 x 128B A-chunk (overlaps Ah1)
    char* Ah1 = lds;                 // 64 x 256B h1 (bf16, swizzled)
    char* Xs  = lds + 16384;         // 64 x 256B X-half (bf16, swizzled)
    char* Bs  = lds + 32768;         // 16KB weight chunk buffer
    const int t = threadIdx.x;
    const int w = t >> 6, lane = t & 63;
    const int r0 = blockIdx.x * 64;
    const int c = lane & 15, sub = lane >> 4;

    // ---- part 1: T = agg @ Wo (K=128 in 2 chunks of 64) ----
    f32x4 acc0[8] = {};
    #pragma unroll
    for (int k0 = 0; k0 < 128; k0 += 64) {
        {
            int row = t >> 2;
            int c16 = (t & 3) * 32;
            const char* ap = (const char*)(qb + (size_t)(r0 + row) * 128 + k0);
            float4 a0 = *(const float4*)(ap + c16);
            float4 a1 = *(const float4*)(ap + c16 + 16);
            *(float4*)(AsA + row * 128 + ((c16)      ^ ((row & 7) << 4))) = a0;
            *(float4*)(AsA + row * 128 + ((c16 + 16) ^ ((row & 7) << 4))) = a1;
        }
        {
            int row = t >> 1;
            int c16 = (t & 1) * 64;
            const char* bp = (const char*)(wo_t + (size_t)row * 128 + k0);
            #pragma unroll
            for (int j = 0; j < 4; j++) {
                float4 b = *(const float4*)(bp + c16 + j * 16);
                *(float4*)(Bs + row * 128 + ((c16 + j * 16) ^ ((row & 7) << 4))) = b;
            }
        }
        __syncthreads();
        #pragma unroll
        for (int kk = 0; kk < 2; kk++) {
            int kbyte = kk * 64 + sub * 16;
            int rowa = w * 16 + c;
            bf16x8 af = *(const bf16x8*)(AsA + rowa * 128 + (kbyte ^ ((rowa & 7) << 4)));
            #pragma unroll
            for (int n = 0; n < 8; n++) {
                int rowb = n * 16 + c;
                bf16x8 bf8 = *(const bf16x8*)(Bs + rowb * 128 + (kbyte ^ ((rowb & 7) << 4)));
                acc0[n] = __builtin_amdgcn_mfma_f32_16x16x32_bf16(af, bf8, acc0[n], 0, 0, 0);
            }
        }
        __syncthreads();
    }

    // ---- LN1: h1 in regs + Ah1 in LDS (bf16) ----
    float h1v[8][4];
    {
        float bsv[8], gv[8], bev[8];
        #pragma unroll
        for (int n = 0; n < 8; n++) {
            int col = n * 16 + c;
            bsv[n] = bo[col]; gv[n] = g1[col]; bev[n] = be1[col];
        }
        #pragma unroll
        for (int i = 0; i < 4; i++) {
            int row = r0 + w * 16 + sub * 4 + i;
            bool ok = row < N_NODES;
            float x[8];
            float s = 0.f;
            #pragma unroll
            for (int n = 0; n < 8; n++) {
                float res = ok ? h[(size_t)row * D + n * 16 + c] : 0.f;
                x[n] = res + acc0[n][i] + bsv[n];
                s += x[n];
            }
            s += __shfl_xor(s, 1); s += __shfl_xor(s, 2);
            s += __shfl_xor(s, 4); s += __shfl_xor(s, 8);
            float mean = s * (1.f / 128.f);
            float v = 0.f;
            #pragma unroll
            for (int n = 0; n < 8; n++) { float dd = x[n] - mean; v += dd * dd; }
            v += __shfl_xor(v, 1); v += __shfl_xor(v, 2);
            v += __shfl_xor(v, 4); v += __shfl_xor(v, 8);
            float rstd = rsqrtf(v * (1.f / 128.f) + 1e-5f);
            int lrow = w * 16 + sub * 4 + i;
            #pragma unroll
            for (int n = 0; n < 8; n++) {
                float o = (x[n] - mean) * rstd * gv[n] + bev[n];
                h1v[n][i] = o;
                int byte = (n * 16 + c) * 2;
                int addr = lrow * 256 + ((byte & ~15) ^ ((lrow & 7) << 4)) + (byte & 15);
                *(u16*)(Ah1 + addr) = bfbits(o);
            }
        }
    }
    __syncthreads();

    // ---- parts 2+3 interleaved per 128-hidden half ----
    f32x4 acc2[8] = {};
    #pragma unroll
    for (int xh = 0; xh < 2; xh++) {
        f32x4 acc1[8] = {};
        #pragma unroll
        for (int kc = 0; kc < 2; kc++) {
            {
                int row = t >> 1;
                int off = (t & 1) * 64;
                const char* bp = (const char*)Wf1t + (size_t)(xh * 128 + row) * 256 + kc * 128 + off;
                #pragma unroll
                for (int j = 0; j < 4; j++) {
                    float4 v = *(const float4*)(bp + j * 16);
                    *(float4*)(Bs + row * 128 + ((off + j * 16) ^ ((row & 7) << 4))) = v;
                }
            }
            __syncthreads();
            #pragma unroll
            for (int kkl = 0; kkl < 2; kkl++) {
                int abyte = (kc * 2 + kkl) * 64 + sub * 16;
                int rowa = w * 16 + c;
                bf16x8 af = *(const bf16x8*)(Ah1 + rowa * 256 + (abyte ^ ((rowa & 7) << 4)));
                int bbyte = kkl * 64 + sub * 16;
                #pragma unroll
                for (int n = 0; n < 8; n++) {
                    int rowb = n * 16 + c;
                    bf16x8 bf8 = *(const bf16x8*)(Bs + rowb * 128 + (bbyte ^ ((rowb & 7) << 4)));
                    acc1[n] = __builtin_amdgcn_mfma_f32_16x16x32_bf16(af, bf8, acc1[n], 0, 0, 0);
                }
            }
            __syncthreads();
        }
        #pragma unroll
        for (int n = 0; n < 8; n++) {
            float bs = b1[xh * 128 + n * 16 + c];
            #pragma unroll
            for (int i = 0; i < 4; i++) {
                int row = w * 16 + sub * 4 + i;
                float v = fmaxf(acc1[n][i] + bs, 0.f);
                int byte = (n * 16 + c) * 2;
                int addr = row * 256 + ((byte & ~15) ^ ((row & 7) << 4)) + (byte & 15);
                *(u16*)(Xs + addr) = bfbits(v);
            }
        }
        __syncthreads();
        #pragma unroll
        for (int oh = 0; oh < 2; oh++) {
            {
                int row = t >> 2;
                int off = (t & 3) * 64;
                const char* bp = (const char*)Wf2t + (size_t)(oh * 64 + row) * 512 + xh * 256 + off;
                #pragma unroll
                for (int j = 0; j < 4; j++) {
                    float4 v = *(const float4*)(bp + j * 16);
                    *(float4*)(Bs + row * 256 + ((off + j * 16) ^ ((row & 7) << 4))) = v;
                }
            }
            __syncthreads();
            #pragma unroll
            for (int kkl = 0; kkl < 4; kkl++) {
                int xbyte = kkl * 64 + sub * 16;
                int rowa = w * 16 + c;
                bf16x8 af = *(const bf16x8*)(Xs + rowa * 256 + (xbyte ^ ((rowa & 7) << 4)));
                #pragma unroll
                for (int n = 0; n < 4; n++) {
                    int rowb = n * 16 + c;
                    bf16x8 bf8 = *(const bf16x8*)(Bs + rowb * 256 + (xbyte ^ ((rowb & 7) << 4)));
                    acc2[oh * 4 + n] = __builtin_amdgcn_mfma_f32_16x16x32_bf16(af, bf8, acc2[oh * 4 + n], 0, 0, 0);
                }
            }
            __syncthreads();
        }
    }

    // ---- LN2 epilogue ----
    {
        float bsv[8], gv[8], bev[8];
        #pragma unroll
        for (int n = 0; n < 8; n++) {
            int col = n * 16 + c;
            bsv[n] = b2[col]; gv[n] = g2[col]; bev[n] = be2[col];
        }
        #pragma unroll
        for (int i = 0; i < 4; i++) {
            int row = r0 + w * 16 + sub * 4 + i;
            bool ok = row < N_NODES;
            float x[8];
            float s = 0.f;
            #pragma unroll
            for (int n = 0; n < 8; n++) {
                x[n] = h1v[n][i] + acc2[n][i] + bsv[n];
                s += x[n];
            }
            s += __shfl_xor(s, 1); s += __shfl_xor(s, 2);
            s += __shfl_xor(s, 4); s += __shfl_xor(s, 8);
            float mean = s * (1.f / 128.f);
            float v = 0.f;
            #pragma unroll
            for (int n = 0; n < 8; n++) { float dd = x[n] - mean; v += dd * dd; }
            v += __shfl_xor(v, 1); v += __shfl_xor(v, 2);
            v += __shfl_xor(v, 4); v += __shfl_xor(v, 8);
            float rstd = rsqrtf(v * (1.f / 128.f) + 1e-5f);
            if (ok) {
                #pragma unroll
                for (int n = 0; n < 8; n++) {
                    float o = (x[n] - mean) * rstd * gv[n] + bev[n];
                    h [(size_t)row * D + n * 16 + c] = o;
                    hb[(size_t)row * D + n * 16 + c] = __float2bfloat16(o);
                }
            }
        }
    }
}

// Fused single-pass attention: q from qb [M][128], KV-interleaved kvb [M][256].
__global__ __launch_bounds__(256) void attn_fused(
    const bf16* __restrict__ qb, const bf16* __restrict__ kvb,
    const int* __restrict__ cnt, const u16* __restrict__ ssrc,
    bf16* __restrict__ aggout)
{
    const float S2 = 0.25f * 1.44269504088896f;   // scale/ln2
    int wid = threadIdx.x >> 6, lane = threadIdx.x & 63;
    int d = blockIdx.x * 4 + wid;
    if (d >= N_NODES) return;
    int slot = lane >> 3, h = lane & 7;

    const u32* qr = (const u32*)(qb + (size_t)d * 128 + h * DH);
    float qf[16];
    {
        uint4 q0 = *(const uint4*)(qr);
        uint4 q1 = *(const uint4*)(qr + 4);
        qf[0]=bflo(q0.x); qf[1]=bfhi(q0.x); qf[2]=bflo(q0.y); qf[3]=bfhi(q0.y);
        qf[4]=bflo(q0.z); qf[5]=bfhi(q0.z); qf[6]=bflo(q0.w); qf[7]=bfhi(q0.w);
        qf[8]=bflo(q1.x); qf[9]=bfhi(q1.x); qf[10]=bflo(q1.y); qf[11]=bfhi(q1.y);
        qf[12]=bflo(q1.z); qf[13]=bfhi(q1.z); qf[14]=bflo(q1.w); qf[15]=bfhi(q1.w);
    }

    int deg = cnt[d];
    if (deg > CAP) deg = CAP;
    const u16* bp = ssrc + (size_t)d * CAP;
    float m2 = -INFINITY, den = 0.f;
    float acc[16] = {};

    for (int i = slot; i < deg; i += 8) {
        int s = bp[i];
        const uint4* kvp = (const uint4*)(kvb + (size_t)s * 256 + h * 32);
        uint4 k0 = kvp[0], k1 = kvp[1], v0 = kvp[2], v1 = kvp[3];
        float p = qf[0]*bflo(k0.x) + qf[1]*bfhi(k0.x)
                + qf[2]*bflo(k0.y) + qf[3]*bfhi(k0.y)
                + qf[4]*bflo(k0.z) + qf[5]*bfhi(k0.z)
                + qf[6]*bflo(k0.w) + qf[7]*bfhi(k0.w)
                + qf[8]*bflo(k1.x) + qf[9]*bfhi(k1.x)
                + qf[10]*bflo(k1.y) + qf[11]*bfhi(k1.y)
                + qf[12]*bflo(k1.z) + qf[13]*bfhi(k1.z)
                + qf[14]*bflo(k1.w) + qf[15]*bfhi(k1.w);
        float p2 = p * S2;
        float w;
        if (p2 > m2 + 8.f) {
            float f = exp2f(m2 - p2);
            den *= f;
            #pragma unroll
            for (int j = 0; j < 16; j++) acc[j] *= f;
            m2 = p2;
            w = 1.f;
        } else {
            w = exp2f(p2 - m2);
        }
        den += w;
        acc[0]  += w*bflo(v0.x); acc[1]  += w*bfhi(v0.x);
        acc[2]  += w*bflo(v0.y); acc[3]  += w*bfhi(v0.y);
        acc[4]  += w*bflo(v0.z); acc[5]  += w*bfhi(v0.z);
        acc[6]  += w*bflo(v0.w); acc[7]  += w*bfhi(v0.w);
        acc[8]  += w*bflo(v1.x); acc[9]  += w*bfhi(v1.x);
        acc[10] += w*bflo(v1.y); acc[11] += w*bfhi(v1.y);
        acc[12] += w*bflo(v1.z); acc[13] += w*bfhi(v1.z);
        acc[14] += w*bflo(v1.w); acc[15] += w*bfhi(v1.w);
    }

    #pragma unroll
    for (int o = 8; o < 64; o <<= 1) {
        float om   = __shfl_xor(m2, o);
        float oden = __shfl_xor(den, o);
        float M = fmaxf(m2, om);
        float fa = (m2 > -INFINITY) ? exp2f(m2 - M) : 0.f;
        float fb = (om > -INFINITY) ? exp2f(om - M) : 0.f;
        den = den * fa + oden * fb;
        #pragma unroll
        for (int j = 0; j < 16; j++) {
            float oa = __shfl_xor(acc[j], o);
            acc[j] = acc[j] * fa + oa * fb;
        }
        m2 = M;
    }

    float r = 1.f / (den + 1e-9f);
    float o0 = 0.f, o1 = 0.f;
    #pragma unroll
    for (int j = 0; j < 8; j++) {
        if (slot == j) { o0 = acc[2 * j]; o1 = acc[2 * j + 1]; }
    }
    bf16* op = aggout + (size_t)d * 128 + h * DH + slot * 2;
    op[0] = __float2bfloat16(o0 * r);
    op[1] = __float2bfloat16(o1 * r);
}

// predictor: 512 blocks x 256 threads; Wp1/bp1/Wp2 staged in LDS once per block;
// each wave processes 8 pairs. Same accumulation order as before -> bit-identical.
__global__ __launch_bounds__(256) void predict_kernel(
    const float* __restrict__ h,
    const int* __restrict__ ps, const int* __restrict__ pd,
    const int* __restrict__ ns, const int* __restrict__ nd,
    const float* __restrict__ Wp1, const float* __restrict__ bp1,
    const float* __restrict__ Wp2, const float* __restrict__ bp2,
    float* __restrict__ out)
{
    __shared__ float Wp1s[8192];   // [128][64]
    __shared__ float bp1s[64], wp2s[64];
    __shared__ float zbuf[4][128];
    const int t = threadIdx.x;
    const int wv = t >> 6, lane = t & 63;
    for (int j = t; j < 8192; j += 256) Wp1s[j] = Wp1[j];
    if (t < 64) { bp1s[t] = bp1[t]; wp2s[t] = Wp2[t]; }
    __syncthreads();

    #pragma unroll
    for (int it = 0; it < 8; it++) {
        int p = blockIdx.x * 32 + wv * 8 + it;
        int a, b;
        if (p < PP) { a = ps[p]; b = pd[p]; }
        else        { a = ns[p - PP]; b = nd[p - PP]; }
        zbuf[wv][lane]      = h[(size_t)a * D + lane]      * h[(size_t)b * D + lane];
        zbuf[wv][lane + 64] = h[(size_t)a * D + lane + 64] * h[(size_t)b * D + lane + 64];
        __syncthreads();
        float acc = bp1s[lane];
        #pragma unroll 4
        for (int i = 0; i < 128; i++) acc += zbuf[wv][i] * Wp1s[i * 64 + lane];
        acc = acc > 0.f ? acc : 0.2f * acc;
        float part = acc * wp2s[lane];
        #pragma unroll
        for (int o = 32; o > 0; o >>= 1) part += __shfl_down(part, o);
        if (lane == 0) out[p] = part + bp2[0];
        __syncthreads();
    }
}

extern "C" void kernel_launch(void* const* d_in, const int* in_sizes, int n_in,
                              void* d_out, int out_size, void* d_ws, size_t ws_size,
                              hipStream_t stream)
{
    const float* x       = (const float*)d_in[0];
    const int*   src     = (const int*)d_in[1];
    const int*   dst     = (const int*)d_in[2];
    const int*   pos_src = (const int*)d_in[3];
    const int*   pos_dst = (const int*)d_in[4];
    const int*   neg_src = (const int*)d_in[5];
    const int*   neg_dst = (const int*)d_in[6];
    const float* W_in = (const float*)d_in[7];
    const float* b_in = (const float*)d_in[8];
    const float* Wq = (const float*)d_in[9];
    const float* bq = (const float*)d_in[10];
    const float* Wk = (const float*)d_in[11];
    const float* bk = (const float*)d_in[12];
    const float* Wv = (const float*)d_in[13];
    const float* bv = (const float*)d_in[14];
    const float* Wo = (const float*)d_in[15];
    const float* bo = (const float*)d_in[16];
    const float* ln1g = (const float*)d_in[17];
    const float* ln1b = (const float*)d_in[18];
    const float* Wf1 = (const float*)d_in[19];
    const float* bf1 = (const float*)d_in[20];
    const float* Wf2 = (const float*)d_in[21];
    const float* bf2 = (const float*)d_in[22];
    const float* ln2g = (const float*)d_in[23];
    const float* ln2b = (const float*)d_in[24];
    const float* Wp1 = (const float*)d_in[25];
    const float* bp1 = (const float*)d_in[26];
    const float* Wp2 = (const float*)d_in[27];
    const float* bp2 = (const float*)d_in[28];

    float* out = (float*)d_out;
    float* h   = out + 2 * PP;                      // [N,D] f32 residual stream

    // workspace layout
    bf16* B    = (bf16*)d_ws;
    bf16* qb   = B;                                 // [MPAD][128]
    bf16* kvb  = B + (size_t)MPAD * 128;            // [MPAD][256] kv-interleaved
    bf16* hb   = B + (size_t)MPAD * 384;            // [MPAD][128]
    int*  cnt  = (int*)(hb + (size_t)MPAD * 128);   // [2][N]
    u16*  ssrc = (u16*)(cnt + 2 * N_NODES);         // [2][N*CAP]
    bf16* wtb  = (bf16*)(ssrc + (size_t)2 * N_NODES * CAP);
    bf16* win_t  = wtb;                             // 16384
    bf16* wqkv_t = wtb + 16384;                     // 2*49152 (kv-interleave perm)
    bf16* wo_t   = wtb + 16384 + 98304;             // 2*16384
    bf16* wf1_t  = wtb + 16384 + 98304 + 32768;     // 2*32768
    bf16* wf2_t  = wtb + 16384 + 98304 + 32768 + 65536; // 2*32768
    float* bqkv  = (float*)(wtb + 16384 + 98304 + 32768 + 65536 + 65536); // [L][384]
    int*  gbin_cnt = (int*)(bqkv + NLAYER * 384);   // [2][NBIN]
    u32*  gbin     = (u32*)(gbin_cnt + 2 * NBIN);   // [2][NBIN][GCAP]

    auto cdiv = [](int a, int b) { return (a + b - 1) / b; };
    const int GX = MPAD / 128;                      // 391
    const int GL = MPAD / 64;                       // 782

    // weight prep (+ gbin_cnt zero), CSR build
    prep_kernel<<<1093, 256, 0, stream>>>(W_in, Wq, Wk, Wv, Wo, Wf1, Wf2, bq, bk, bv,
                                          win_t, wqkv_t, wo_t, wf1_t, wf2_t, bqkv, gbin_cnt);
    bin_kernel<<<dim3(cdiv(NE, CHUNK), 2), 256, 0, stream>>>(dst, src, gbin, gbin_cnt);
    expand_kernel<<<dim3(NBIN, 2), 256, 0, stream>>>(gbin, gbin_cnt, cnt, ssrc);

    // h = x @ W_in + b_in
    gemm_in<<<dim3(GX, 1), 256, 0, stream>>>(x, win_t, b_in, h, hb);

    for (int l = 0; l < NLAYER; l++) {
        gemm_qkv<<<dim3(GX, 3), 256, 0, stream>>>(hb, wqkv_t + l * 49152, bqkv + l * 384, qb, kvb);

        attn_fused<<<cdiv(N_NODES, 4), 256, 0, stream>>>(qb, kvb, cnt + l * N_NODES,
                                                         ssrc + (size_t)l * N_NODES * CAP, qb);

        tail_fused<<<GL, 256, 0, stream>>>(qb, wo_t + l * 16384, bo + l * D,
                                           ln1g + l * D, ln1b + l * D,
                                           wf1_t + l * 32768, bf1 + l * FF,
                                           wf2_t + l * 32768, bf2 + l * D,
                                           ln2g + l * D, ln2b + l * D, h, hb);
    }

    predict_kernel<<<512, 256, 0, stream>>>(h, pos_src, pos_dst, neg_src, neg_dst,
                                            Wp1, bp1, Wp2, bp2, out);
}